// Round 1
// baseline (1081.282 us; speedup 1.0000x reference)
//
#include <hip/hip_runtime.h>
#include <math.h>

#define N_NODES 50000
#define N_EDGES 1600000
#define DIM     128
#define N_GRAPHS 64

// ---------------- CSR build ----------------

__global__ void count_k(const int* __restrict__ col, int* __restrict__ cnt) {
    int i = blockIdx.x * blockDim.x + threadIdx.x;
    int stride = gridDim.x * blockDim.x;
    for (; i < N_EDGES; i += stride) atomicAdd(&cnt[col[i]], 1);
}

// per-block exclusive scan (512 elems) + block totals
__global__ void scan1_k(const int* __restrict__ cnt, int* __restrict__ offs, int* __restrict__ part) {
    __shared__ int sm[512];
    int gid = blockIdx.x * 512 + threadIdx.x;
    int v = (gid < N_NODES) ? cnt[gid] : 0;
    sm[threadIdx.x] = v;
    __syncthreads();
    for (int off = 1; off < 512; off <<= 1) {
        int t = 0;
        if (threadIdx.x >= off) t = sm[threadIdx.x - off];
        __syncthreads();
        if (threadIdx.x >= off) sm[threadIdx.x] += t;
        __syncthreads();
    }
    if (gid < N_NODES) offs[gid] = sm[threadIdx.x] - v;   // exclusive within block
    if (threadIdx.x == 511) part[blockIdx.x] = sm[511];
}

__global__ void scan2_k(int* __restrict__ part, int nb) {
    if (threadIdx.x == 0 && blockIdx.x == 0) {
        int s = 0;
        for (int i = 0; i < nb; ++i) { int t = part[i]; part[i] = s; s += t; }
    }
}

__global__ void scan3_k(int* __restrict__ offs, const int* __restrict__ part,
                        const int* __restrict__ cnt, float* __restrict__ dis) {
    int i = blockIdx.x * blockDim.x + threadIdx.x;
    if (i < N_NODES) {
        offs[i] += part[i >> 9];
        dis[i] = rsqrtf((float)cnt[i] + 1.0f);
    }
}

__global__ void fill_k(const int* __restrict__ col, const int* __restrict__ row,
                       const int* __restrict__ offs, int* __restrict__ fill,
                       int* __restrict__ csr) {
    int i = blockIdx.x * blockDim.x + threadIdx.x;
    int stride = gridDim.x * blockDim.x;
    for (; i < N_EDGES; i += stride) {
        int c = col[i];
        int p = offs[c] + atomicAdd(&fill[c], 1);
        csr[p] = row[i];
    }
}

// ---------------- g = (x @ W) * dis[row]  ----------------
// block: 256 threads = 8 rows x 32 col-groups (float4). W staged in LDS (64KB).
__global__ __launch_bounds__(256) void gemm_scale_k(const float* __restrict__ x,
                                                    const float* __restrict__ W,
                                                    const float* __restrict__ dis,
                                                    float* __restrict__ g) {
    __shared__ float4 Wl[4096];   // [k][cg] : 128 x 32 float4 = 64KB
    const float4* W4 = (const float4*)W;
    #pragma unroll
    for (int i = 0; i < 16; ++i) Wl[threadIdx.x + 256 * i] = W4[threadIdx.x + 256 * i];
    __syncthreads();

    int r  = blockIdx.x * 8 + (threadIdx.x >> 5);   // 6250*8 = 50000 exactly
    int cg = threadIdx.x & 31;
    const float4* xr = (const float4*)(x + (size_t)r * DIM);
    float4 acc = make_float4(0.f, 0.f, 0.f, 0.f);
    #pragma unroll
    for (int k4 = 0; k4 < 32; ++k4) {
        float4 a = xr[k4];
        float4 w;
        w = Wl[(k4 * 4 + 0) * 32 + cg];
        acc.x = fmaf(a.x, w.x, acc.x); acc.y = fmaf(a.x, w.y, acc.y);
        acc.z = fmaf(a.x, w.z, acc.z); acc.w = fmaf(a.x, w.w, acc.w);
        w = Wl[(k4 * 4 + 1) * 32 + cg];
        acc.x = fmaf(a.y, w.x, acc.x); acc.y = fmaf(a.y, w.y, acc.y);
        acc.z = fmaf(a.y, w.z, acc.z); acc.w = fmaf(a.y, w.w, acc.w);
        w = Wl[(k4 * 4 + 2) * 32 + cg];
        acc.x = fmaf(a.z, w.x, acc.x); acc.y = fmaf(a.z, w.y, acc.y);
        acc.z = fmaf(a.z, w.z, acc.z); acc.w = fmaf(a.z, w.w, acc.w);
        w = Wl[(k4 * 4 + 3) * 32 + cg];
        acc.x = fmaf(a.w, w.x, acc.x); acc.y = fmaf(a.w, w.y, acc.y);
        acc.z = fmaf(a.w, w.z, acc.z); acc.w = fmaf(a.w, w.w, acc.w);
    }
    float dsc = dis[r];
    float4 o = make_float4(acc.x * dsc, acc.y * dsc, acc.z * dsc, acc.w * dsc);
    ((float4*)(g + (size_t)r * DIM))[cg] = o;
}

// ---------------- out_i = relu(dis_i * (g_i + sum_{j->i} g_j) + b) ----------------
// one wave per node; lane holds float2 (128 floats / 64 lanes)
__global__ __launch_bounds__(256) void agg_k(const float* __restrict__ g,
                                             const float* __restrict__ dis,
                                             const int* __restrict__ csr,
                                             const int* __restrict__ offs,
                                             const int* __restrict__ cnt,
                                             const float* __restrict__ bias,
                                             float* __restrict__ out) {
    int lane = threadIdx.x & 63;
    int node = blockIdx.x * 4 + (threadIdx.x >> 6);
    if (node >= N_NODES) return;

    const float2* gn = (const float2*)(g + (size_t)node * DIM);
    float2 acc = gn[lane];                       // self term g_i
    int base = offs[node];
    int c = cnt[node];
    for (int s0 = 0; s0 < c; s0 += 64) {
        int rem = c - s0;
        int m = rem < 64 ? rem : 64;
        int idx = 0;
        if (lane < m) idx = csr[base + s0 + lane];
        for (int t = 0; t < m; ++t) {
            int j = __shfl(idx, t, 64);
            float2 v = ((const float2*)(g + (size_t)j * DIM))[lane];
            acc.x += v.x; acc.y += v.y;
        }
    }
    float d = dis[node];
    float2 bv = ((const float2*)bias)[lane];
    float2 o;
    o.x = fmaxf(fmaf(acc.x, d, bv.x), 0.f);
    o.y = fmaxf(fmaf(acc.y, d, bv.y), 0.f);
    ((float2*)(out + (size_t)node * DIM))[lane] = o;
}

// ---------------- mean-pool accumulate ----------------
__global__ __launch_bounds__(256) void pool_k(const float* __restrict__ h,
                                              const int* __restrict__ batch,
                                              float* __restrict__ pooled,
                                              float* __restrict__ counts) {
    int lane = threadIdx.x & 63;
    int node = blockIdx.x * 4 + (threadIdx.x >> 6);
    if (node >= N_NODES) return;
    int b = batch[node];
    float2 v = ((const float2*)(h + (size_t)node * DIM))[lane];
    atomicAdd(&pooled[b * DIM + lane * 2], v.x);
    atomicAdd(&pooled[b * DIM + lane * 2 + 1], v.y);
    if (lane == 0) atomicAdd(&counts[b], 1.0f);
}

// ---------------- head: sigmoid(pooled/cnt @ Wf + bf) ----------------
__global__ void final_k(const float* __restrict__ pooled, const float* __restrict__ counts,
                        const float* __restrict__ Wf, const float* __restrict__ bf,
                        float* __restrict__ out) {
    __shared__ float sred[2];
    int gidx = blockIdx.x;
    int tid = threadIdx.x;   // 128 threads
    float c = fmaxf(counts[gidx], 1.0f);
    float v = pooled[gidx * DIM + tid] / c * Wf[tid];
    for (int off = 32; off > 0; off >>= 1) v += __shfl_down(v, off, 64);
    if ((tid & 63) == 0) sred[tid >> 6] = v;
    __syncthreads();
    if (tid == 0) {
        float t = sred[0] + sred[1] + bf[0];
        out[gidx] = 1.0f / (1.0f + expf(-t));
    }
}

extern "C" void kernel_launch(void* const* d_in, const int* in_sizes, int n_in,
                              void* d_out, int out_size, void* d_ws, size_t ws_size,
                              hipStream_t stream) {
    const float* x     = (const float*)d_in[0];
    const int*   ei    = (const int*)d_in[1];
    const int*   batch = (const int*)d_in[2];
    const float* W1 = (const float*)d_in[3];  const float* b1 = (const float*)d_in[4];
    const float* W2 = (const float*)d_in[5];  const float* b2 = (const float*)d_in[6];
    const float* W3 = (const float*)d_in[7];  const float* b3 = (const float*)d_in[8];
    const float* Wf = (const float*)d_in[9];  const float* bf = (const float*)d_in[10];
    const int* rowp = ei;              // edge_index[0] = source
    const int* colp = ei + N_EDGES;    // edge_index[1] = target

    char* ws = (char*)d_ws;
    size_t o = 0;
    auto alloc = [&](size_t bytes) -> void* {
        void* p = ws + o;
        o += (bytes + 255) & ~(size_t)255;
        return p;
    };
    int*   cnt    = (int*)  alloc((size_t)N_NODES * 4);
    int*   offs   = (int*)  alloc((size_t)N_NODES * 4);
    int*   fill   = (int*)  alloc((size_t)N_NODES * 4);
    int*   part   = (int*)  alloc(1024 * 4);
    float* dis    = (float*)alloc((size_t)N_NODES * 4);
    int*   csr    = (int*)  alloc((size_t)N_EDGES * 4);
    float* pooled = (float*)alloc((size_t)(N_GRAPHS * DIM + N_GRAPHS) * 4);
    float* bufA   = (float*)alloc((size_t)N_NODES * DIM * 4);
    float* bufB   = (float*)alloc((size_t)N_NODES * DIM * 4);
    float* counts = pooled + N_GRAPHS * DIM;

    hipMemsetAsync(cnt, 0, (size_t)N_NODES * 4, stream);
    hipMemsetAsync(fill, 0, (size_t)N_NODES * 4, stream);
    hipMemsetAsync(pooled, 0, (size_t)(N_GRAPHS * DIM + N_GRAPHS) * 4, stream);

    int nb = (N_NODES + 511) / 512;
    count_k<<<512, 256, 0, stream>>>(colp, cnt);
    scan1_k<<<nb, 512, 0, stream>>>(cnt, offs, part);
    scan2_k<<<1, 64, 0, stream>>>(part, nb);
    scan3_k<<<(N_NODES + 255) / 256, 256, 0, stream>>>(offs, part, cnt, dis);
    fill_k<<<512, 256, 0, stream>>>(colp, rowp, offs, fill, csr);

    // layer 1: g = (x@W1)*dis -> bufA ; agg -> bufB
    gemm_scale_k<<<N_NODES / 8, 256, 0, stream>>>(x, W1, dis, bufA);
    agg_k<<<(N_NODES + 3) / 4, 256, 0, stream>>>(bufA, dis, csr, offs, cnt, b1, bufB);
    // layer 2
    gemm_scale_k<<<N_NODES / 8, 256, 0, stream>>>(bufB, W2, dis, bufA);
    agg_k<<<(N_NODES + 3) / 4, 256, 0, stream>>>(bufA, dis, csr, offs, cnt, b2, bufB);
    // layer 3
    gemm_scale_k<<<N_NODES / 8, 256, 0, stream>>>(bufB, W3, dis, bufA);
    agg_k<<<(N_NODES + 3) / 4, 256, 0, stream>>>(bufA, dis, csr, offs, cnt, b3, bufB);

    pool_k<<<(N_NODES + 3) / 4, 256, 0, stream>>>(bufB, batch, pooled, counts);
    final_k<<<N_GRAPHS, 128, 0, stream>>>(pooled, counts, Wf, bf, (float*)d_out);
}

// Round 2
// 729.712 us; speedup vs baseline: 1.4818x; 1.4818x over previous
//
#include <hip/hip_runtime.h>
#include <math.h>

#define N_NODES 50000
#define N_EDGES 1600000
#define DIM     128
#define N_GRAPHS 64

// ---------------- CSR build ----------------

__global__ void count_k(const int* __restrict__ col, int* __restrict__ cnt) {
    int i = blockIdx.x * blockDim.x + threadIdx.x;
    int stride = gridDim.x * blockDim.x;
    for (; i < N_EDGES; i += stride) atomicAdd(&cnt[col[i]], 1);
}

// per-block exclusive scan (512 elems) + block totals
__global__ void scan1_k(const int* __restrict__ cnt, int* __restrict__ offs, int* __restrict__ part) {
    __shared__ int sm[512];
    int gid = blockIdx.x * 512 + threadIdx.x;
    int v = (gid < N_NODES) ? cnt[gid] : 0;
    sm[threadIdx.x] = v;
    __syncthreads();
    for (int off = 1; off < 512; off <<= 1) {
        int t = 0;
        if (threadIdx.x >= off) t = sm[threadIdx.x - off];
        __syncthreads();
        if (threadIdx.x >= off) sm[threadIdx.x] += t;
        __syncthreads();
    }
    if (gid < N_NODES) offs[gid] = sm[threadIdx.x] - v;   // exclusive within block
    if (threadIdx.x == 511) part[blockIdx.x] = sm[511];
}

__global__ void scan2_k(int* __restrict__ part, int nb) {
    if (threadIdx.x == 0 && blockIdx.x == 0) {
        int s = 0;
        for (int i = 0; i < nb; ++i) { int t = part[i]; part[i] = s; s += t; }
    }
}

__global__ void scan3_k(int* __restrict__ offs, const int* __restrict__ part,
                        const int* __restrict__ cnt, float* __restrict__ dis) {
    int i = blockIdx.x * blockDim.x + threadIdx.x;
    if (i < N_NODES) {
        offs[i] += part[i >> 9];
        dis[i] = rsqrtf((float)cnt[i] + 1.0f);
    }
}

__global__ void fill_k(const int* __restrict__ col, const int* __restrict__ row,
                       const int* __restrict__ offs, int* __restrict__ fill,
                       int* __restrict__ csr) {
    int i = blockIdx.x * blockDim.x + threadIdx.x;
    int stride = gridDim.x * blockDim.x;
    for (; i < N_EDGES; i += stride) {
        int c = col[i];
        int p = offs[c] + atomicAdd(&fill[c], 1);
        csr[p] = row[i];
    }
}

// ---------------- g = (x @ W) * dis[row]  ----------------
// block: 256 threads = 8 rows x 32 col-groups (float4). W staged in LDS (64KB).
__global__ __launch_bounds__(256) void gemm_scale_k(const float* __restrict__ x,
                                                    const float* __restrict__ W,
                                                    const float* __restrict__ dis,
                                                    float* __restrict__ g) {
    __shared__ float4 Wl[4096];   // [k][cg] : 128 x 32 float4 = 64KB
    const float4* W4 = (const float4*)W;
    #pragma unroll
    for (int i = 0; i < 16; ++i) Wl[threadIdx.x + 256 * i] = W4[threadIdx.x + 256 * i];
    __syncthreads();

    int r  = blockIdx.x * 8 + (threadIdx.x >> 5);   // 6250*8 = 50000 exactly
    int cg = threadIdx.x & 31;
    const float4* xr = (const float4*)(x + (size_t)r * DIM);
    float4 acc = make_float4(0.f, 0.f, 0.f, 0.f);
    #pragma unroll
    for (int k4 = 0; k4 < 32; ++k4) {
        float4 a = xr[k4];
        float4 w;
        w = Wl[(k4 * 4 + 0) * 32 + cg];
        acc.x = fmaf(a.x, w.x, acc.x); acc.y = fmaf(a.x, w.y, acc.y);
        acc.z = fmaf(a.x, w.z, acc.z); acc.w = fmaf(a.x, w.w, acc.w);
        w = Wl[(k4 * 4 + 1) * 32 + cg];
        acc.x = fmaf(a.y, w.x, acc.x); acc.y = fmaf(a.y, w.y, acc.y);
        acc.z = fmaf(a.y, w.z, acc.z); acc.w = fmaf(a.y, w.w, acc.w);
        w = Wl[(k4 * 4 + 2) * 32 + cg];
        acc.x = fmaf(a.z, w.x, acc.x); acc.y = fmaf(a.z, w.y, acc.y);
        acc.z = fmaf(a.z, w.z, acc.z); acc.w = fmaf(a.z, w.w, acc.w);
        w = Wl[(k4 * 4 + 3) * 32 + cg];
        acc.x = fmaf(a.w, w.x, acc.x); acc.y = fmaf(a.w, w.y, acc.y);
        acc.z = fmaf(a.w, w.z, acc.z); acc.w = fmaf(a.w, w.w, acc.w);
    }
    float dsc = dis[r];
    float4 o = make_float4(acc.x * dsc, acc.y * dsc, acc.z * dsc, acc.w * dsc);
    ((float4*)(g + (size_t)r * DIM))[cg] = o;
}

// ---------------- out_i = relu(dis_i * (g_i + sum_{j->i} g_j) + b) ----------------
// one wave per node; lane holds float2 (128 floats / 64 lanes)
__global__ __launch_bounds__(256) void agg_k(const float* __restrict__ g,
                                             const float* __restrict__ dis,
                                             const int* __restrict__ csr,
                                             const int* __restrict__ offs,
                                             const int* __restrict__ cnt,
                                             const float* __restrict__ bias,
                                             float* __restrict__ out) {
    int lane = threadIdx.x & 63;
    int node = blockIdx.x * 4 + (threadIdx.x >> 6);
    if (node >= N_NODES) return;

    const float2* gn = (const float2*)(g + (size_t)node * DIM);
    float2 acc = gn[lane];                       // self term g_i
    int base = offs[node];
    int c = cnt[node];
    for (int s0 = 0; s0 < c; s0 += 64) {
        int rem = c - s0;
        int m = rem < 64 ? rem : 64;
        int idx = 0;
        if (lane < m) idx = csr[base + s0 + lane];
        for (int t = 0; t < m; ++t) {
            int j = __shfl(idx, t, 64);
            float2 v = ((const float2*)(g + (size_t)j * DIM))[lane];
            acc.x += v.x; acc.y += v.y;
        }
    }
    float d = dis[node];
    float2 bv = ((const float2*)bias)[lane];
    float2 o;
    o.x = fmaxf(fmaf(acc.x, d, bv.x), 0.f);
    o.y = fmaxf(fmaf(acc.y, d, bv.y), 0.f);
    ((float2*)(out + (size_t)node * DIM))[lane] = o;
}

// ---------------- mean-pool: batch is SORTED -> per-block register accumulation,
// flush one atomic per (block x graph boundary). 128 threads, thread = feature col.
#define POOL_BLOCKS 512
__global__ __launch_bounds__(128) void pool_k(const float* __restrict__ h,
                                              const int* __restrict__ batch,
                                              float* __restrict__ pooled,
                                              float* __restrict__ counts) {
    const int chunk = (N_NODES + POOL_BLOCKS - 1) / POOL_BLOCKS;  // 98
    int tid = threadIdx.x;
    int start = blockIdx.x * chunk;
    int end = start + chunk; if (end > N_NODES) end = N_NODES;
    if (start >= end) return;

    float acc = 0.f;
    int cur = batch[start];
    int cl = 0;
    for (int n = start; n < end; ++n) {
        int b = batch[n];
        if (b != cur) {
            atomicAdd(&pooled[cur * DIM + tid], acc);
            if (tid == 0) atomicAdd(&counts[cur], (float)cl);
            acc = 0.f; cl = 0; cur = b;
        }
        acc += h[(size_t)n * DIM + tid];
        ++cl;
    }
    atomicAdd(&pooled[cur * DIM + tid], acc);
    if (tid == 0) atomicAdd(&counts[cur], (float)cl);
}

// ---------------- head: sigmoid(pooled/cnt @ Wf + bf) ----------------
__global__ void final_k(const float* __restrict__ pooled, const float* __restrict__ counts,
                        const float* __restrict__ Wf, const float* __restrict__ bf,
                        float* __restrict__ out) {
    __shared__ float sred[2];
    int gidx = blockIdx.x;
    int tid = threadIdx.x;   // 128 threads
    float c = fmaxf(counts[gidx], 1.0f);
    float v = pooled[gidx * DIM + tid] / c * Wf[tid];
    for (int off = 32; off > 0; off >>= 1) v += __shfl_down(v, off, 64);
    if ((tid & 63) == 0) sred[tid >> 6] = v;
    __syncthreads();
    if (tid == 0) {
        float t = sred[0] + sred[1] + bf[0];
        out[gidx] = 1.0f / (1.0f + expf(-t));
    }
}

extern "C" void kernel_launch(void* const* d_in, const int* in_sizes, int n_in,
                              void* d_out, int out_size, void* d_ws, size_t ws_size,
                              hipStream_t stream) {
    const float* x     = (const float*)d_in[0];
    const int*   ei    = (const int*)d_in[1];
    const int*   batch = (const int*)d_in[2];
    const float* W1 = (const float*)d_in[3];  const float* b1 = (const float*)d_in[4];
    const float* W2 = (const float*)d_in[5];  const float* b2 = (const float*)d_in[6];
    const float* W3 = (const float*)d_in[7];  const float* b3 = (const float*)d_in[8];
    const float* Wf = (const float*)d_in[9];  const float* bf = (const float*)d_in[10];
    const int* rowp = ei;              // edge_index[0] = source
    const int* colp = ei + N_EDGES;    // edge_index[1] = target

    char* ws = (char*)d_ws;
    size_t o = 0;
    auto alloc = [&](size_t bytes) -> void* {
        void* p = ws + o;
        o += (bytes + 255) & ~(size_t)255;
        return p;
    };
    int*   cnt    = (int*)  alloc((size_t)N_NODES * 4);
    int*   offs   = (int*)  alloc((size_t)N_NODES * 4);
    int*   fill   = (int*)  alloc((size_t)N_NODES * 4);
    int*   part   = (int*)  alloc(1024 * 4);
    float* dis    = (float*)alloc((size_t)N_NODES * 4);
    int*   csr    = (int*)  alloc((size_t)N_EDGES * 4);
    float* pooled = (float*)alloc((size_t)(N_GRAPHS * DIM + N_GRAPHS) * 4);
    float* bufA   = (float*)alloc((size_t)N_NODES * DIM * 4);
    float* bufB   = (float*)alloc((size_t)N_NODES * DIM * 4);
    float* counts = pooled + N_GRAPHS * DIM;

    hipMemsetAsync(cnt, 0, (size_t)N_NODES * 4, stream);
    hipMemsetAsync(fill, 0, (size_t)N_NODES * 4, stream);
    hipMemsetAsync(pooled, 0, (size_t)(N_GRAPHS * DIM + N_GRAPHS) * 4, stream);

    int nb = (N_NODES + 511) / 512;
    count_k<<<512, 256, 0, stream>>>(colp, cnt);
    scan1_k<<<nb, 512, 0, stream>>>(cnt, offs, part);
    scan2_k<<<1, 64, 0, stream>>>(part, nb);
    scan3_k<<<(N_NODES + 255) / 256, 256, 0, stream>>>(offs, part, cnt, dis);
    fill_k<<<512, 256, 0, stream>>>(colp, rowp, offs, fill, csr);

    // layer 1: g = (x@W1)*dis -> bufA ; agg -> bufB
    gemm_scale_k<<<N_NODES / 8, 256, 0, stream>>>(x, W1, dis, bufA);
    agg_k<<<(N_NODES + 3) / 4, 256, 0, stream>>>(bufA, dis, csr, offs, cnt, b1, bufB);
    // layer 2
    gemm_scale_k<<<N_NODES / 8, 256, 0, stream>>>(bufB, W2, dis, bufA);
    agg_k<<<(N_NODES + 3) / 4, 256, 0, stream>>>(bufA, dis, csr, offs, cnt, b2, bufB);
    // layer 3
    gemm_scale_k<<<N_NODES / 8, 256, 0, stream>>>(bufB, W3, dis, bufA);
    agg_k<<<(N_NODES + 3) / 4, 256, 0, stream>>>(bufA, dis, csr, offs, cnt, b3, bufB);

    pool_k<<<POOL_BLOCKS, 128, 0, stream>>>(bufB, batch, pooled, counts);
    final_k<<<N_GRAPHS, 128, 0, stream>>>(pooled, counts, Wf, bf, (float*)d_out);
}

// Round 3
// 599.357 us; speedup vs baseline: 1.8041x; 1.2175x over previous
//
#include <hip/hip_runtime.h>
#include <math.h>

#define N_NODES 50000
#define N_EDGES 1600000
#define DIM     128
#define N_GRAPHS 64

typedef unsigned int uint32;
typedef unsigned short ushort16;

static __device__ __forceinline__ ushort f2b(float f) {
    uint32 u = __float_as_uint(f);
    uint32 r = (u + 0x7fffu + ((u >> 16) & 1u)) >> 16;   // RNE
    return (ushort)r;
}
static __device__ __forceinline__ float b2f(ushort h) {
    return __uint_as_float(((uint32)h) << 16);
}

// ---------------- CSR build ----------------

__global__ void count_k(const int* __restrict__ col, int* __restrict__ cnt) {
    int i = blockIdx.x * blockDim.x + threadIdx.x;
    int stride = gridDim.x * blockDim.x;
    for (; i < N_EDGES; i += stride) atomicAdd(&cnt[col[i]], 1);
}

__global__ void scan1_k(const int* __restrict__ cnt, int* __restrict__ offs, int* __restrict__ part) {
    __shared__ int sm[512];
    int gid = blockIdx.x * 512 + threadIdx.x;
    int v = (gid < N_NODES) ? cnt[gid] : 0;
    sm[threadIdx.x] = v;
    __syncthreads();
    for (int off = 1; off < 512; off <<= 1) {
        int t = 0;
        if (threadIdx.x >= off) t = sm[threadIdx.x - off];
        __syncthreads();
        if (threadIdx.x >= off) sm[threadIdx.x] += t;
        __syncthreads();
    }
    if (gid < N_NODES) offs[gid] = sm[threadIdx.x] - v;
    if (threadIdx.x == 511) part[blockIdx.x] = sm[511];
}

__global__ void scan2_k(int* __restrict__ part, int nb) {
    if (threadIdx.x == 0 && blockIdx.x == 0) {
        int s = 0;
        for (int i = 0; i < nb; ++i) { int t = part[i]; part[i] = s; s += t; }
    }
}

__global__ void scan3_k(int* __restrict__ offs, const int* __restrict__ part,
                        const int* __restrict__ cnt, float* __restrict__ dis) {
    int i = blockIdx.x * blockDim.x + threadIdx.x;
    if (i < N_NODES) {
        offs[i] += part[i >> 9];
        dis[i] = rsqrtf((float)cnt[i] + 1.0f);
    }
}

__global__ void fill_k(const int* __restrict__ col, const int* __restrict__ row,
                       const int* __restrict__ offs, int* __restrict__ fill,
                       int* __restrict__ csr) {
    int i = blockIdx.x * blockDim.x + threadIdx.x;
    int stride = gridDim.x * blockDim.x;
    for (; i < N_EDGES; i += stride) {
        int c = col[i];
        int p = offs[c] + atomicAdd(&fill[c], 1);
        csr[p] = row[i];
    }
}

// ---------------- fp32 -> bf16 convert ----------------
__global__ __launch_bounds__(256) void conv_k(const float* __restrict__ x, ushort* __restrict__ xb) {
    int i = blockIdx.x * blockDim.x + threadIdx.x;   // over float4 groups
    const int n4 = N_NODES * DIM / 4;
    if (i >= n4) return;
    float4 v = ((const float4*)x)[i];
    ushort4 o;
    o.x = f2b(v.x); o.y = f2b(v.y); o.z = f2b(v.z); o.w = f2b(v.w);
    ((ushort4*)xb)[i] = o;
}

// ---------------- g = bf16( (h_bf @ W) * dis )  ----------------
// 256 threads = 8 rows x 32 col-groups (float4 of output). W fp32 in LDS.
__global__ __launch_bounds__(256) void gemm_scale_k(const ushort* __restrict__ xb,
                                                    const float* __restrict__ W,
                                                    const float* __restrict__ dis,
                                                    ushort* __restrict__ gb) {
    __shared__ float4 Wl[4096];   // [k][cg] : 128 x 32 float4 = 64KB
    const float4* W4 = (const float4*)W;
    #pragma unroll
    for (int i = 0; i < 16; ++i) Wl[threadIdx.x + 256 * i] = W4[threadIdx.x + 256 * i];
    __syncthreads();

    int r  = blockIdx.x * 8 + (threadIdx.x >> 5);
    int cg = threadIdx.x & 31;
    const ushort4* xr = (const ushort4*)(xb + (size_t)r * DIM);  // 4 bf16 / 8B
    float4 acc = make_float4(0.f, 0.f, 0.f, 0.f);
    #pragma unroll
    for (int k4 = 0; k4 < 32; ++k4) {
        ushort4 a4 = xr[k4];
        float ax = b2f(a4.x), ay = b2f(a4.y), az = b2f(a4.z), aw = b2f(a4.w);
        float4 w;
        w = Wl[(k4 * 4 + 0) * 32 + cg];
        acc.x = fmaf(ax, w.x, acc.x); acc.y = fmaf(ax, w.y, acc.y);
        acc.z = fmaf(ax, w.z, acc.z); acc.w = fmaf(ax, w.w, acc.w);
        w = Wl[(k4 * 4 + 1) * 32 + cg];
        acc.x = fmaf(ay, w.x, acc.x); acc.y = fmaf(ay, w.y, acc.y);
        acc.z = fmaf(ay, w.z, acc.z); acc.w = fmaf(ay, w.w, acc.w);
        w = Wl[(k4 * 4 + 2) * 32 + cg];
        acc.x = fmaf(az, w.x, acc.x); acc.y = fmaf(az, w.y, acc.y);
        acc.z = fmaf(az, w.z, acc.z); acc.w = fmaf(az, w.w, acc.w);
        w = Wl[(k4 * 4 + 3) * 32 + cg];
        acc.x = fmaf(aw, w.x, acc.x); acc.y = fmaf(aw, w.y, acc.y);
        acc.z = fmaf(aw, w.z, acc.z); acc.w = fmaf(aw, w.w, acc.w);
    }
    float dsc = dis[r];
    ushort4 o;
    o.x = f2b(acc.x * dsc); o.y = f2b(acc.y * dsc);
    o.z = f2b(acc.z * dsc); o.w = f2b(acc.w * dsc);
    ((ushort4*)(gb + (size_t)r * DIM))[cg] = o;
}

// ---------------- out = bf16( relu(dis_i * (g_i + sum_j g_j) + b) ) ----------------
// one wave per node; lane holds 2 bf16 (4B). 8-wide ILP on gathers.
__global__ __launch_bounds__(256) void agg_k(const ushort* __restrict__ gb,
                                             const float* __restrict__ dis,
                                             const int* __restrict__ csr,
                                             const int* __restrict__ offs,
                                             const int* __restrict__ cnt,
                                             const float* __restrict__ bias,
                                             ushort* __restrict__ outb) {
    int lane = threadIdx.x & 63;
    int node = blockIdx.x * 4 + (threadIdx.x >> 6);
    if (node >= N_NODES) return;

    uint32 s = *(const uint32*)(gb + ((size_t)node << 7) + (lane << 1));
    float2 acc;
    acc.x = __uint_as_float(s << 16);
    acc.y = __uint_as_float(s & 0xffff0000u);

    int base = offs[node];
    int c = cnt[node];
    for (int s0 = 0; s0 < c; s0 += 64) {
        int rem = c - s0;
        int m = rem < 64 ? rem : 64;
        int idx = 0;
        if (lane < m) idx = csr[base + s0 + lane];
        int t = 0;
        for (; t + 8 <= m; t += 8) {
            int j0 = __shfl(idx, t, 64),     j1 = __shfl(idx, t + 1, 64);
            int j2 = __shfl(idx, t + 2, 64), j3 = __shfl(idx, t + 3, 64);
            int j4 = __shfl(idx, t + 4, 64), j5 = __shfl(idx, t + 5, 64);
            int j6 = __shfl(idx, t + 6, 64), j7 = __shfl(idx, t + 7, 64);
            uint32 v0 = *(const uint32*)(gb + ((size_t)j0 << 7) + (lane << 1));
            uint32 v1 = *(const uint32*)(gb + ((size_t)j1 << 7) + (lane << 1));
            uint32 v2 = *(const uint32*)(gb + ((size_t)j2 << 7) + (lane << 1));
            uint32 v3 = *(const uint32*)(gb + ((size_t)j3 << 7) + (lane << 1));
            uint32 v4 = *(const uint32*)(gb + ((size_t)j4 << 7) + (lane << 1));
            uint32 v5 = *(const uint32*)(gb + ((size_t)j5 << 7) + (lane << 1));
            uint32 v6 = *(const uint32*)(gb + ((size_t)j6 << 7) + (lane << 1));
            uint32 v7 = *(const uint32*)(gb + ((size_t)j7 << 7) + (lane << 1));
            acc.x += __uint_as_float(v0 << 16); acc.y += __uint_as_float(v0 & 0xffff0000u);
            acc.x += __uint_as_float(v1 << 16); acc.y += __uint_as_float(v1 & 0xffff0000u);
            acc.x += __uint_as_float(v2 << 16); acc.y += __uint_as_float(v2 & 0xffff0000u);
            acc.x += __uint_as_float(v3 << 16); acc.y += __uint_as_float(v3 & 0xffff0000u);
            acc.x += __uint_as_float(v4 << 16); acc.y += __uint_as_float(v4 & 0xffff0000u);
            acc.x += __uint_as_float(v5 << 16); acc.y += __uint_as_float(v5 & 0xffff0000u);
            acc.x += __uint_as_float(v6 << 16); acc.y += __uint_as_float(v6 & 0xffff0000u);
            acc.x += __uint_as_float(v7 << 16); acc.y += __uint_as_float(v7 & 0xffff0000u);
        }
        for (; t < m; ++t) {
            int j = __shfl(idx, t, 64);
            uint32 v = *(const uint32*)(gb + ((size_t)j << 7) + (lane << 1));
            acc.x += __uint_as_float(v << 16);
            acc.y += __uint_as_float(v & 0xffff0000u);
        }
    }
    float d = dis[node];
    float bx = bias[lane * 2], by = bias[lane * 2 + 1];
    float ox = fmaxf(fmaf(acc.x, d, bx), 0.f);
    float oy = fmaxf(fmaf(acc.y, d, by), 0.f);
    uint32 packed = (uint32)f2b(ox) | ((uint32)f2b(oy) << 16);
    *(uint32*)(outb + ((size_t)node << 7) + (lane << 1)) = packed;
}

// ---------------- mean-pool: batch sorted -> register accumulation ----------------
#define POOL_BLOCKS 512
__global__ __launch_bounds__(128) void pool_k(const ushort* __restrict__ hb,
                                              const int* __restrict__ batch,
                                              float* __restrict__ pooled,
                                              float* __restrict__ counts) {
    const int chunk = (N_NODES + POOL_BLOCKS - 1) / POOL_BLOCKS;  // 98
    int tid = threadIdx.x;
    int start = blockIdx.x * chunk;
    int end = start + chunk; if (end > N_NODES) end = N_NODES;
    if (start >= end) return;

    float acc = 0.f;
    int cur = batch[start];
    int cl = 0;
    for (int n = start; n < end; ++n) {
        int b = batch[n];
        if (b != cur) {
            atomicAdd(&pooled[cur * DIM + tid], acc);
            if (tid == 0) atomicAdd(&counts[cur], (float)cl);
            acc = 0.f; cl = 0; cur = b;
        }
        acc += b2f(hb[((size_t)n << 7) + tid]);
        ++cl;
    }
    atomicAdd(&pooled[cur * DIM + tid], acc);
    if (tid == 0) atomicAdd(&counts[cur], (float)cl);
}

// ---------------- head ----------------
__global__ void final_k(const float* __restrict__ pooled, const float* __restrict__ counts,
                        const float* __restrict__ Wf, const float* __restrict__ bf,
                        float* __restrict__ out) {
    __shared__ float sred[2];
    int gidx = blockIdx.x;
    int tid = threadIdx.x;   // 128
    float c = fmaxf(counts[gidx], 1.0f);
    float v = pooled[gidx * DIM + tid] / c * Wf[tid];
    for (int off = 32; off > 0; off >>= 1) v += __shfl_down(v, off, 64);
    if ((tid & 63) == 0) sred[tid >> 6] = v;
    __syncthreads();
    if (tid == 0) {
        float t = sred[0] + sred[1] + bf[0];
        out[gidx] = 1.0f / (1.0f + expf(-t));
    }
}

extern "C" void kernel_launch(void* const* d_in, const int* in_sizes, int n_in,
                              void* d_out, int out_size, void* d_ws, size_t ws_size,
                              hipStream_t stream) {
    const float* x     = (const float*)d_in[0];
    const int*   ei    = (const int*)d_in[1];
    const int*   batch = (const int*)d_in[2];
    const float* W1 = (const float*)d_in[3];  const float* b1 = (const float*)d_in[4];
    const float* W2 = (const float*)d_in[5];  const float* b2 = (const float*)d_in[6];
    const float* W3 = (const float*)d_in[7];  const float* b3 = (const float*)d_in[8];
    const float* Wf = (const float*)d_in[9];  const float* bf = (const float*)d_in[10];
    const int* rowp = ei;              // sources
    const int* colp = ei + N_EDGES;    // targets

    char* ws = (char*)d_ws;
    size_t o = 0;
    auto alloc = [&](size_t bytes) -> void* {
        void* p = ws + o;
        o += (bytes + 255) & ~(size_t)255;
        return p;
    };
    int*    cnt    = (int*)   alloc((size_t)N_NODES * 4);
    int*    offs   = (int*)   alloc((size_t)N_NODES * 4);
    int*    fill   = (int*)   alloc((size_t)N_NODES * 4);
    int*    part   = (int*)   alloc(1024 * 4);
    float*  dis    = (float*) alloc((size_t)N_NODES * 4);
    int*    csr    = (int*)   alloc((size_t)N_EDGES * 4);
    float*  pooled = (float*) alloc((size_t)(N_GRAPHS * DIM + N_GRAPHS) * 4);
    ushort* bufA   = (ushort*)alloc((size_t)N_NODES * DIM * 2);   // g tables
    ushort* bufB   = (ushort*)alloc((size_t)N_NODES * DIM * 2);   // x_bf / h
    float*  counts = pooled + N_GRAPHS * DIM;

    hipMemsetAsync(cnt, 0, (size_t)N_NODES * 4, stream);
    hipMemsetAsync(fill, 0, (size_t)N_NODES * 4, stream);
    hipMemsetAsync(pooled, 0, (size_t)(N_GRAPHS * DIM + N_GRAPHS) * 4, stream);

    int nb = (N_NODES + 511) / 512;
    count_k<<<512, 256, 0, stream>>>(colp, cnt);
    scan1_k<<<nb, 512, 0, stream>>>(cnt, offs, part);
    scan2_k<<<1, 64, 0, stream>>>(part, nb);
    scan3_k<<<(N_NODES + 255) / 256, 256, 0, stream>>>(offs, part, cnt, dis);
    fill_k<<<512, 256, 0, stream>>>(colp, rowp, offs, fill, csr);

    conv_k<<<(N_NODES * DIM / 4 + 255) / 256, 256, 0, stream>>>(x, bufB);

    // layer 1
    gemm_scale_k<<<N_NODES / 8, 256, 0, stream>>>(bufB, W1, dis, bufA);
    agg_k<<<(N_NODES + 3) / 4, 256, 0, stream>>>(bufA, dis, csr, offs, cnt, b1, bufB);
    // layer 2
    gemm_scale_k<<<N_NODES / 8, 256, 0, stream>>>(bufB, W2, dis, bufA);
    agg_k<<<(N_NODES + 3) / 4, 256, 0, stream>>>(bufA, dis, csr, offs, cnt, b2, bufB);
    // layer 3
    gemm_scale_k<<<N_NODES / 8, 256, 0, stream>>>(bufB, W3, dis, bufA);
    agg_k<<<(N_NODES + 3) / 4, 256, 0, stream>>>(bufA, dis, csr, offs, cnt, b3, bufB);

    pool_k<<<POOL_BLOCKS, 128, 0, stream>>>(bufB, batch, pooled, counts);
    final_k<<<N_GRAPHS, 128, 0, stream>>>(pooled, counts, Wf, bf, (float*)d_out);
}

// Round 4
// 538.268 us; speedup vs baseline: 2.0088x; 1.1135x over previous
//
#include <hip/hip_runtime.h>
#include <math.h>

#define N_NODES 50000
#define N_EDGES 1600000
#define DIM     128
#define N_GRAPHS 64

typedef unsigned int uint32;

static __device__ __forceinline__ ushort f2b(float f) {
    uint32 u = __float_as_uint(f);
    uint32 r = (u + 0x7fffu + ((u >> 16) & 1u)) >> 16;   // RNE
    return (ushort)r;
}
static __device__ __forceinline__ float b2f(ushort h) {
    return __uint_as_float(((uint32)h) << 16);
}

// ---------------- CSR build ----------------

__global__ void count_k(const int* __restrict__ col, int* __restrict__ cnt) {
    int i = blockIdx.x * blockDim.x + threadIdx.x;
    int stride = gridDim.x * blockDim.x;
    for (; i < N_EDGES; i += stride) atomicAdd(&cnt[col[i]], 1);
}

__global__ void scan1_k(const int* __restrict__ cnt, int* __restrict__ offs, int* __restrict__ part) {
    __shared__ int sm[512];
    int gid = blockIdx.x * 512 + threadIdx.x;
    int v = (gid < N_NODES) ? cnt[gid] : 0;
    sm[threadIdx.x] = v;
    __syncthreads();
    for (int off = 1; off < 512; off <<= 1) {
        int t = 0;
        if (threadIdx.x >= off) t = sm[threadIdx.x - off];
        __syncthreads();
        if (threadIdx.x >= off) sm[threadIdx.x] += t;
        __syncthreads();
    }
    if (gid < N_NODES) offs[gid] = sm[threadIdx.x] - v;
    if (threadIdx.x == 511) part[blockIdx.x] = sm[511];
}

__global__ void scan2_k(int* __restrict__ part, int nb) {
    if (threadIdx.x == 0 && blockIdx.x == 0) {
        int s = 0;
        for (int i = 0; i < nb; ++i) { int t = part[i]; part[i] = s; s += t; }
    }
}

__global__ void scan3_k(int* __restrict__ offs, const int* __restrict__ part,
                        const int* __restrict__ cnt, float* __restrict__ dis) {
    int i = blockIdx.x * blockDim.x + threadIdx.x;
    if (i < N_NODES) {
        offs[i] += part[i >> 9];
        dis[i] = rsqrtf((float)cnt[i] + 1.0f);
    }
}

// ---- bucketed two-pass csr fill ----
#define NBUK 196            // ceil(50000/256) buckets, bucket = c >> 8
#define PB1  400
#define CHUNK1 (N_EDGES / PB1)   // 4000 exact

__global__ void initb_k(const int* __restrict__ offs, int* __restrict__ gfill) {
    int t = threadIdx.x;
    if (t < NBUK) gfill[t] = offs[t << 8];
}

// pass 1: bin edges into bucket-contiguous packed array. runs are block-private.
__global__ __launch_bounds__(256) void bin_k(const int* __restrict__ col,
                                             const int* __restrict__ row,
                                             int* __restrict__ gfill,
                                             uint32* __restrict__ packed) {
    __shared__ int hist[NBUK];
    __shared__ int cur[NBUK];
    int tid = threadIdx.x;
    for (int t = tid; t < NBUK; t += 256) hist[t] = 0;
    __syncthreads();
    int start = blockIdx.x * CHUNK1, end = start + CHUNK1;
    for (int e = start + tid; e < end; e += 256)
        atomicAdd(&hist[col[e] >> 8], 1);
    __syncthreads();
    for (int t = tid; t < NBUK; t += 256) {
        int h = hist[t];
        cur[t] = h ? atomicAdd(&gfill[t], h) : 0;
    }
    __syncthreads();
    for (int e = start + tid; e < end; e += 256) {
        int c = col[e];
        int r = row[e];
        int pos = atomicAdd(&cur[c >> 8], 1);
        packed[pos] = ((uint32)(c & 255) << 16) | (uint32)r;
    }
}

// pass 2: one block owns one bucket's csr region (single-XCD write locality)
__global__ __launch_bounds__(256) void fill2_k(const uint32* __restrict__ packed,
                                               const int* __restrict__ offs,
                                               int* __restrict__ csr) {
    __shared__ int loffs[256];
    __shared__ int lfill[256];
    int b = blockIdx.x;
    int tid = threadIdx.x;
    int node0 = b << 8;
    int node = node0 + tid;
    loffs[tid] = (node < N_NODES) ? offs[node] : N_EDGES;
    lfill[tid] = 0;
    int rs = offs[node0];
    int en = node0 + 256;
    int re = (en >= N_NODES) ? N_EDGES : offs[en];
    __syncthreads();
    for (int e = rs + tid; e < re; e += 256) {
        uint32 p = packed[e];
        int cl = p >> 16;
        int rank = atomicAdd(&lfill[cl], 1);
        csr[loffs[cl] + rank] = (int)(p & 0xffffu);
    }
}

// ---------------- fp32 -> bf16 convert ----------------
__global__ __launch_bounds__(256) void conv_k(const float* __restrict__ x, ushort* __restrict__ xb) {
    int i = blockIdx.x * blockDim.x + threadIdx.x;
    const int n4 = N_NODES * DIM / 4;
    if (i >= n4) return;
    float4 v = ((const float4*)x)[i];
    ushort4 o;
    o.x = f2b(v.x); o.y = f2b(v.y); o.z = f2b(v.z); o.w = f2b(v.w);
    ((ushort4*)xb)[i] = o;
}

// ---------------- g = bf16( (h_bf @ W) * dis )  ----------------
__global__ __launch_bounds__(256) void gemm_scale_k(const ushort* __restrict__ xb,
                                                    const float* __restrict__ W,
                                                    const float* __restrict__ dis,
                                                    ushort* __restrict__ gb) {
    __shared__ float4 Wl[4096];   // [k][cg] : 128 x 32 float4 = 64KB
    const float4* W4 = (const float4*)W;
    #pragma unroll
    for (int i = 0; i < 16; ++i) Wl[threadIdx.x + 256 * i] = W4[threadIdx.x + 256 * i];
    __syncthreads();

    int r  = blockIdx.x * 8 + (threadIdx.x >> 5);
    int cg = threadIdx.x & 31;
    const ushort4* xr = (const ushort4*)(xb + (size_t)r * DIM);
    float4 acc = make_float4(0.f, 0.f, 0.f, 0.f);
    #pragma unroll
    for (int k4 = 0; k4 < 32; ++k4) {
        ushort4 a4 = xr[k4];
        float ax = b2f(a4.x), ay = b2f(a4.y), az = b2f(a4.z), aw = b2f(a4.w);
        float4 w;
        w = Wl[(k4 * 4 + 0) * 32 + cg];
        acc.x = fmaf(ax, w.x, acc.x); acc.y = fmaf(ax, w.y, acc.y);
        acc.z = fmaf(ax, w.z, acc.z); acc.w = fmaf(ax, w.w, acc.w);
        w = Wl[(k4 * 4 + 1) * 32 + cg];
        acc.x = fmaf(ay, w.x, acc.x); acc.y = fmaf(ay, w.y, acc.y);
        acc.z = fmaf(ay, w.z, acc.z); acc.w = fmaf(ay, w.w, acc.w);
        w = Wl[(k4 * 4 + 2) * 32 + cg];
        acc.x = fmaf(az, w.x, acc.x); acc.y = fmaf(az, w.y, acc.y);
        acc.z = fmaf(az, w.z, acc.z); acc.w = fmaf(az, w.w, acc.w);
        w = Wl[(k4 * 4 + 3) * 32 + cg];
        acc.x = fmaf(aw, w.x, acc.x); acc.y = fmaf(aw, w.y, acc.y);
        acc.z = fmaf(aw, w.z, acc.z); acc.w = fmaf(aw, w.w, acc.w);
    }
    float dsc = dis[r];
    ushort4 o;
    o.x = f2b(acc.x * dsc); o.y = f2b(acc.y * dsc);
    o.z = f2b(acc.z * dsc); o.w = f2b(acc.w * dsc);
    ((ushort4*)(gb + (size_t)r * DIM))[cg] = o;
}

// ---------------- out = bf16( relu(dis_i * (g_i + sum_j g_j) + b) ) ----------------
__global__ __launch_bounds__(256) void agg_k(const ushort* __restrict__ gb,
                                             const float* __restrict__ dis,
                                             const int* __restrict__ csr,
                                             const int* __restrict__ offs,
                                             const int* __restrict__ cnt,
                                             const float* __restrict__ bias,
                                             ushort* __restrict__ outb) {
    int lane = threadIdx.x & 63;
    int node = blockIdx.x * 4 + (threadIdx.x >> 6);
    if (node >= N_NODES) return;

    uint32 s = *(const uint32*)(gb + ((size_t)node << 7) + (lane << 1));
    float2 acc;
    acc.x = __uint_as_float(s << 16);
    acc.y = __uint_as_float(s & 0xffff0000u);

    int base = offs[node];
    int c = cnt[node];
    for (int s0 = 0; s0 < c; s0 += 64) {
        int rem = c - s0;
        int m = rem < 64 ? rem : 64;
        int idx = 0;
        if (lane < m) idx = csr[base + s0 + lane];
        int t = 0;
        for (; t + 8 <= m; t += 8) {
            int j0 = __shfl(idx, t, 64),     j1 = __shfl(idx, t + 1, 64);
            int j2 = __shfl(idx, t + 2, 64), j3 = __shfl(idx, t + 3, 64);
            int j4 = __shfl(idx, t + 4, 64), j5 = __shfl(idx, t + 5, 64);
            int j6 = __shfl(idx, t + 6, 64), j7 = __shfl(idx, t + 7, 64);
            uint32 v0 = *(const uint32*)(gb + ((size_t)j0 << 7) + (lane << 1));
            uint32 v1 = *(const uint32*)(gb + ((size_t)j1 << 7) + (lane << 1));
            uint32 v2 = *(const uint32*)(gb + ((size_t)j2 << 7) + (lane << 1));
            uint32 v3 = *(const uint32*)(gb + ((size_t)j3 << 7) + (lane << 1));
            uint32 v4 = *(const uint32*)(gb + ((size_t)j4 << 7) + (lane << 1));
            uint32 v5 = *(const uint32*)(gb + ((size_t)j5 << 7) + (lane << 1));
            uint32 v6 = *(const uint32*)(gb + ((size_t)j6 << 7) + (lane << 1));
            uint32 v7 = *(const uint32*)(gb + ((size_t)j7 << 7) + (lane << 1));
            acc.x += __uint_as_float(v0 << 16); acc.y += __uint_as_float(v0 & 0xffff0000u);
            acc.x += __uint_as_float(v1 << 16); acc.y += __uint_as_float(v1 & 0xffff0000u);
            acc.x += __uint_as_float(v2 << 16); acc.y += __uint_as_float(v2 & 0xffff0000u);
            acc.x += __uint_as_float(v3 << 16); acc.y += __uint_as_float(v3 & 0xffff0000u);
            acc.x += __uint_as_float(v4 << 16); acc.y += __uint_as_float(v4 & 0xffff0000u);
            acc.x += __uint_as_float(v5 << 16); acc.y += __uint_as_float(v5 & 0xffff0000u);
            acc.x += __uint_as_float(v6 << 16); acc.y += __uint_as_float(v6 & 0xffff0000u);
            acc.x += __uint_as_float(v7 << 16); acc.y += __uint_as_float(v7 & 0xffff0000u);
        }
        for (; t < m; ++t) {
            int j = __shfl(idx, t, 64);
            uint32 v = *(const uint32*)(gb + ((size_t)j << 7) + (lane << 1));
            acc.x += __uint_as_float(v << 16);
            acc.y += __uint_as_float(v & 0xffff0000u);
        }
    }
    float d = dis[node];
    float bx = bias[lane * 2], by = bias[lane * 2 + 1];
    float ox = fmaxf(fmaf(acc.x, d, bx), 0.f);
    float oy = fmaxf(fmaf(acc.y, d, by), 0.f);
    uint32 packed = (uint32)f2b(ox) | ((uint32)f2b(oy) << 16);
    *(uint32*)(outb + ((size_t)node << 7) + (lane << 1)) = packed;
}

// ---------------- mean-pool ----------------
#define POOL_BLOCKS 512
__global__ __launch_bounds__(128) void pool_k(const ushort* __restrict__ hb,
                                              const int* __restrict__ batch,
                                              float* __restrict__ pooled,
                                              float* __restrict__ counts) {
    const int chunk = (N_NODES + POOL_BLOCKS - 1) / POOL_BLOCKS;  // 98
    int tid = threadIdx.x;
    int start = blockIdx.x * chunk;
    int end = start + chunk; if (end > N_NODES) end = N_NODES;
    if (start >= end) return;

    float acc = 0.f;
    int cur = batch[start];
    int cl = 0;
    for (int n = start; n < end; ++n) {
        int b = batch[n];
        if (b != cur) {
            atomicAdd(&pooled[cur * DIM + tid], acc);
            if (tid == 0) atomicAdd(&counts[cur], (float)cl);
            acc = 0.f; cl = 0; cur = b;
        }
        acc += b2f(hb[((size_t)n << 7) + tid]);
        ++cl;
    }
    atomicAdd(&pooled[cur * DIM + tid], acc);
    if (tid == 0) atomicAdd(&counts[cur], (float)cl);
}

// ---------------- head ----------------
__global__ void final_k(const float* __restrict__ pooled, const float* __restrict__ counts,
                        const float* __restrict__ Wf, const float* __restrict__ bf,
                        float* __restrict__ out) {
    __shared__ float sred[2];
    int gidx = blockIdx.x;
    int tid = threadIdx.x;   // 128
    float c = fmaxf(counts[gidx], 1.0f);
    float v = pooled[gidx * DIM + tid] / c * Wf[tid];
    for (int off = 32; off > 0; off >>= 1) v += __shfl_down(v, off, 64);
    if ((tid & 63) == 0) sred[tid >> 6] = v;
    __syncthreads();
    if (tid == 0) {
        float t = sred[0] + sred[1] + bf[0];
        out[gidx] = 1.0f / (1.0f + expf(-t));
    }
}

extern "C" void kernel_launch(void* const* d_in, const int* in_sizes, int n_in,
                              void* d_out, int out_size, void* d_ws, size_t ws_size,
                              hipStream_t stream) {
    const float* x     = (const float*)d_in[0];
    const int*   ei    = (const int*)d_in[1];
    const int*   batch = (const int*)d_in[2];
    const float* W1 = (const float*)d_in[3];  const float* b1 = (const float*)d_in[4];
    const float* W2 = (const float*)d_in[5];  const float* b2 = (const float*)d_in[6];
    const float* W3 = (const float*)d_in[7];  const float* b3 = (const float*)d_in[8];
    const float* Wf = (const float*)d_in[9];  const float* bf = (const float*)d_in[10];
    const int* rowp = ei;              // sources
    const int* colp = ei + N_EDGES;    // targets

    char* ws = (char*)d_ws;
    size_t o = 0;
    auto alloc = [&](size_t bytes) -> void* {
        void* p = ws + o;
        o += (bytes + 255) & ~(size_t)255;
        return p;
    };
    int*    cnt    = (int*)   alloc((size_t)N_NODES * 4);
    int*    offs   = (int*)   alloc((size_t)N_NODES * 4);
    int*    gfill  = (int*)   alloc(256 * 4);
    int*    part   = (int*)   alloc(1024 * 4);
    float*  dis    = (float*) alloc((size_t)N_NODES * 4);
    int*    csr    = (int*)   alloc((size_t)N_EDGES * 4);
    uint32* packed = (uint32*)alloc((size_t)N_EDGES * 4);
    float*  pooled = (float*) alloc((size_t)(N_GRAPHS * DIM + N_GRAPHS) * 4);
    ushort* bufA   = (ushort*)alloc((size_t)N_NODES * DIM * 2);
    ushort* bufB   = (ushort*)alloc((size_t)N_NODES * DIM * 2);
    float*  counts = pooled + N_GRAPHS * DIM;

    hipMemsetAsync(cnt, 0, (size_t)N_NODES * 4, stream);
    hipMemsetAsync(pooled, 0, (size_t)(N_GRAPHS * DIM + N_GRAPHS) * 4, stream);

    int nb = (N_NODES + 511) / 512;
    count_k<<<512, 256, 0, stream>>>(colp, cnt);
    scan1_k<<<nb, 512, 0, stream>>>(cnt, offs, part);
    scan2_k<<<1, 64, 0, stream>>>(part, nb);
    scan3_k<<<(N_NODES + 255) / 256, 256, 0, stream>>>(offs, part, cnt, dis);
    initb_k<<<1, 256, 0, stream>>>(offs, gfill);
    bin_k<<<PB1, 256, 0, stream>>>(colp, rowp, gfill, packed);
    fill2_k<<<NBUK, 256, 0, stream>>>(packed, offs, csr);

    conv_k<<<(N_NODES * DIM / 4 + 255) / 256, 256, 0, stream>>>(x, bufB);

    // layer 1
    gemm_scale_k<<<N_NODES / 8, 256, 0, stream>>>(bufB, W1, dis, bufA);
    agg_k<<<(N_NODES + 3) / 4, 256, 0, stream>>>(bufA, dis, csr, offs, cnt, b1, bufB);
    // layer 2
    gemm_scale_k<<<N_NODES / 8, 256, 0, stream>>>(bufB, W2, dis, bufA);
    agg_k<<<(N_NODES + 3) / 4, 256, 0, stream>>>(bufA, dis, csr, offs, cnt, b2, bufB);
    // layer 3
    gemm_scale_k<<<N_NODES / 8, 256, 0, stream>>>(bufB, W3, dis, bufA);
    agg_k<<<(N_NODES + 3) / 4, 256, 0, stream>>>(bufA, dis, csr, offs, cnt, b3, bufB);

    pool_k<<<POOL_BLOCKS, 128, 0, stream>>>(bufB, batch, pooled, counts);
    final_k<<<N_GRAPHS, 128, 0, stream>>>(pooled, counts, Wf, bf, (float*)d_out);
}

// Round 5
// 400.005 us; speedup vs baseline: 2.7032x; 1.3457x over previous
//
#include <hip/hip_runtime.h>
#include <math.h>

#define N_NODES 50000
#define N_EDGES 1600000
#define DIM     128
#define N_GRAPHS 64

typedef unsigned int uint32;
typedef __attribute__((ext_vector_type(8))) short bf16x8;
typedef __attribute__((ext_vector_type(4))) float f32x4;

static __device__ __forceinline__ ushort f2b(float f) {
    uint32 u = __float_as_uint(f);
    uint32 r = (u + 0x7fffu + ((u >> 16) & 1u)) >> 16;   // RNE
    return (ushort)r;
}
static __device__ __forceinline__ float b2f(ushort h) {
    return __uint_as_float(((uint32)h) << 16);
}

// ---------------- CSR build ----------------

__global__ void count_k(const int* __restrict__ col, int* __restrict__ cnt) {
    int i = blockIdx.x * blockDim.x + threadIdx.x;
    int stride = gridDim.x * blockDim.x;
    for (; i < N_EDGES; i += stride) atomicAdd(&cnt[col[i]], 1);
}

__global__ void scan1_k(const int* __restrict__ cnt, int* __restrict__ offs, int* __restrict__ part) {
    __shared__ int sm[512];
    int gid = blockIdx.x * 512 + threadIdx.x;
    int v = (gid < N_NODES) ? cnt[gid] : 0;
    sm[threadIdx.x] = v;
    __syncthreads();
    for (int off = 1; off < 512; off <<= 1) {
        int t = 0;
        if (threadIdx.x >= off) t = sm[threadIdx.x - off];
        __syncthreads();
        if (threadIdx.x >= off) sm[threadIdx.x] += t;
        __syncthreads();
    }
    if (gid < N_NODES) offs[gid] = sm[threadIdx.x] - v;
    if (threadIdx.x == 511) part[blockIdx.x] = sm[511];
}

__global__ void scan2_k(int* __restrict__ part, int nb) {
    if (threadIdx.x == 0 && blockIdx.x == 0) {
        int s = 0;
        for (int i = 0; i < nb; ++i) { int t = part[i]; part[i] = s; s += t; }
    }
}

__global__ void scan3_k(int* __restrict__ offs, const int* __restrict__ part,
                        const int* __restrict__ cnt, float* __restrict__ dis) {
    int i = blockIdx.x * blockDim.x + threadIdx.x;
    if (i < N_NODES) {
        offs[i] += part[i >> 9];
        dis[i] = rsqrtf((float)cnt[i] + 1.0f);
    }
}

// ---- bucketed two-pass csr fill ----
#define NBUK 196            // ceil(50000/256) buckets, bucket = c >> 8
#define PB1  400
#define CHUNK1 (N_EDGES / PB1)   // 4000 exact

__global__ void initb_k(const int* __restrict__ offs, int* __restrict__ gfill) {
    int t = threadIdx.x;
    if (t < NBUK) gfill[t] = offs[t << 8];
}

__global__ __launch_bounds__(256) void bin_k(const int* __restrict__ col,
                                             const int* __restrict__ row,
                                             int* __restrict__ gfill,
                                             uint32* __restrict__ packed) {
    __shared__ int hist[NBUK];
    __shared__ int cur[NBUK];
    int tid = threadIdx.x;
    for (int t = tid; t < NBUK; t += 256) hist[t] = 0;
    __syncthreads();
    int start = blockIdx.x * CHUNK1, end = start + CHUNK1;
    for (int e = start + tid; e < end; e += 256)
        atomicAdd(&hist[col[e] >> 8], 1);
    __syncthreads();
    for (int t = tid; t < NBUK; t += 256) {
        int h = hist[t];
        cur[t] = h ? atomicAdd(&gfill[t], h) : 0;
    }
    __syncthreads();
    for (int e = start + tid; e < end; e += 256) {
        int c = col[e];
        int r = row[e];
        int pos = atomicAdd(&cur[c >> 8], 1);
        packed[pos] = ((uint32)(c & 255) << 16) | (uint32)r;
    }
}

__global__ __launch_bounds__(256) void fill2_k(const uint32* __restrict__ packed,
                                               const int* __restrict__ offs,
                                               int* __restrict__ csr) {
    __shared__ int loffs[256];
    __shared__ int lfill[256];
    int b = blockIdx.x;
    int tid = threadIdx.x;
    int node0 = b << 8;
    int node = node0 + tid;
    loffs[tid] = (node < N_NODES) ? offs[node] : N_EDGES;
    lfill[tid] = 0;
    int rs = offs[node0];
    int en = node0 + 256;
    int re = (en >= N_NODES) ? N_EDGES : offs[en];
    __syncthreads();
    for (int e = rs + tid; e < re; e += 256) {
        uint32 p = packed[e];
        int cl = p >> 16;
        int rank = atomicAdd(&lfill[cl], 1);
        csr[loffs[cl] + rank] = (int)(p & 0xffffu);
    }
}

// ---------------- fp32 -> bf16 convert ----------------
__global__ __launch_bounds__(256) void conv_k(const float* __restrict__ x, ushort* __restrict__ xb) {
    int i = blockIdx.x * blockDim.x + threadIdx.x;
    const int n4 = N_NODES * DIM / 4;
    if (i >= n4) return;
    float4 v = ((const float4*)x)[i];
    ushort4 o;
    o.x = f2b(v.x); o.y = f2b(v.y); o.z = f2b(v.z); o.w = f2b(v.w);
    ((ushort4*)xb)[i] = o;
}

// ---------------- W (fp32, row-major [k][n]) -> wt (bf16, [n][k]) ----------------
__global__ __launch_bounds__(256) void wtr_k(const float* __restrict__ W, ushort* __restrict__ wt) {
    int t = blockIdx.x * 256 + threadIdx.x;   // 0..16383
    int n = t >> 7, k = t & 127;
    wt[n * 128 + k] = f2b(W[k * 128 + n]);
}

// ---------------- g = bf16( (h_bf @ W) * dis )  via MFMA ----------------
// 4 waves/block; wave = 16 rows x 128 cols (8 tiles of 16x16), K=128 in 4 steps.
// A: xb row-major (lane: row=l&15, k=kb*32+(l>>4)*8+j).  B: wt=W^T row-major.
// C/D: row=(l>>4)*4+reg, col=l&15 (m89-verified mapping).
__global__ __launch_bounds__(256) void gemm_mfma_k(const ushort* __restrict__ xb,
                                                   const ushort* __restrict__ wt,
                                                   const float* __restrict__ dis,
                                                   ushort* __restrict__ gb) {
    int wid  = threadIdx.x >> 6;
    int lane = threadIdx.x & 63;
    int r0 = blockIdx.x * 64 + wid * 16;
    int m  = lane & 15;
    int kg = lane >> 4;

    int arow = r0 + m;
    if (arow >= N_NODES) arow = N_NODES - 1;   // clamp; results discarded on store
    const ushort* abase = xb + (size_t)arow * DIM + kg * 8;
    const ushort* wbase = wt + (size_t)m * DIM + kg * 8;

    f32x4 acc[8];
    #pragma unroll
    for (int nt = 0; nt < 8; ++nt) acc[nt] = (f32x4){0.f, 0.f, 0.f, 0.f};

    #pragma unroll
    for (int kb = 0; kb < 4; ++kb) {
        bf16x8 a = *(const bf16x8*)(abase + kb * 32);
        #pragma unroll
        for (int nt = 0; nt < 8; ++nt) {
            bf16x8 b = *(const bf16x8*)(wbase + (size_t)nt * 16 * DIM + kb * 32);
            acc[nt] = __builtin_amdgcn_mfma_f32_16x16x32_bf16(a, b, acc[nt], 0, 0, 0);
        }
    }

    int orow0 = r0 + kg * 4;
    float dsc[4];
    #pragma unroll
    for (int i = 0; i < 4; ++i) {
        int rr = orow0 + i;
        dsc[i] = (rr < N_NODES) ? dis[rr] : 0.f;
    }
    #pragma unroll
    for (int i = 0; i < 4; ++i) {
        int rr = orow0 + i;
        if (rr >= N_NODES) continue;
        ushort* orow = gb + (size_t)rr * DIM + m;
        #pragma unroll
        for (int nt = 0; nt < 8; ++nt)
            orow[nt * 16] = f2b(acc[nt][i] * dsc[i]);
    }
}

// ---------------- out = bf16( relu(dis_i * (g_i + sum_j g_j) + b) ) ----------------
__global__ __launch_bounds__(256) void agg_k(const ushort* __restrict__ gb,
                                             const float* __restrict__ dis,
                                             const int* __restrict__ csr,
                                             const int* __restrict__ offs,
                                             const int* __restrict__ cnt,
                                             const float* __restrict__ bias,
                                             ushort* __restrict__ outb) {
    int lane = threadIdx.x & 63;
    int node = blockIdx.x * 4 + (threadIdx.x >> 6);
    if (node >= N_NODES) return;

    uint32 s = *(const uint32*)(gb + ((size_t)node << 7) + (lane << 1));
    float2 acc;
    acc.x = __uint_as_float(s << 16);
    acc.y = __uint_as_float(s & 0xffff0000u);

    int base = offs[node];
    int c = cnt[node];
    for (int s0 = 0; s0 < c; s0 += 64) {
        int rem = c - s0;
        int m = rem < 64 ? rem : 64;
        int idx = 0;
        if (lane < m) idx = csr[base + s0 + lane];
        int t = 0;
        for (; t + 8 <= m; t += 8) {
            int j0 = __shfl(idx, t, 64),     j1 = __shfl(idx, t + 1, 64);
            int j2 = __shfl(idx, t + 2, 64), j3 = __shfl(idx, t + 3, 64);
            int j4 = __shfl(idx, t + 4, 64), j5 = __shfl(idx, t + 5, 64);
            int j6 = __shfl(idx, t + 6, 64), j7 = __shfl(idx, t + 7, 64);
            uint32 v0 = *(const uint32*)(gb + ((size_t)j0 << 7) + (lane << 1));
            uint32 v1 = *(const uint32*)(gb + ((size_t)j1 << 7) + (lane << 1));
            uint32 v2 = *(const uint32*)(gb + ((size_t)j2 << 7) + (lane << 1));
            uint32 v3 = *(const uint32*)(gb + ((size_t)j3 << 7) + (lane << 1));
            uint32 v4 = *(const uint32*)(gb + ((size_t)j4 << 7) + (lane << 1));
            uint32 v5 = *(const uint32*)(gb + ((size_t)j5 << 7) + (lane << 1));
            uint32 v6 = *(const uint32*)(gb + ((size_t)j6 << 7) + (lane << 1));
            uint32 v7 = *(const uint32*)(gb + ((size_t)j7 << 7) + (lane << 1));
            acc.x += __uint_as_float(v0 << 16); acc.y += __uint_as_float(v0 & 0xffff0000u);
            acc.x += __uint_as_float(v1 << 16); acc.y += __uint_as_float(v1 & 0xffff0000u);
            acc.x += __uint_as_float(v2 << 16); acc.y += __uint_as_float(v2 & 0xffff0000u);
            acc.x += __uint_as_float(v3 << 16); acc.y += __uint_as_float(v3 & 0xffff0000u);
            acc.x += __uint_as_float(v4 << 16); acc.y += __uint_as_float(v4 & 0xffff0000u);
            acc.x += __uint_as_float(v5 << 16); acc.y += __uint_as_float(v5 & 0xffff0000u);
            acc.x += __uint_as_float(v6 << 16); acc.y += __uint_as_float(v6 & 0xffff0000u);
            acc.x += __uint_as_float(v7 << 16); acc.y += __uint_as_float(v7 & 0xffff0000u);
        }
        for (; t < m; ++t) {
            int j = __shfl(idx, t, 64);
            uint32 v = *(const uint32*)(gb + ((size_t)j << 7) + (lane << 1));
            acc.x += __uint_as_float(v << 16);
            acc.y += __uint_as_float(v & 0xffff0000u);
        }
    }
    float d = dis[node];
    float bx = bias[lane * 2], by = bias[lane * 2 + 1];
    float ox = fmaxf(fmaf(acc.x, d, bx), 0.f);
    float oy = fmaxf(fmaf(acc.y, d, by), 0.f);
    uint32 packed = (uint32)f2b(ox) | ((uint32)f2b(oy) << 16);
    *(uint32*)(outb + ((size_t)node << 7) + (lane << 1)) = packed;
}

// ---------------- mean-pool ----------------
#define POOL_BLOCKS 512
__global__ __launch_bounds__(128) void pool_k(const ushort* __restrict__ hb,
                                              const int* __restrict__ batch,
                                              float* __restrict__ pooled,
                                              float* __restrict__ counts) {
    const int chunk = (N_NODES + POOL_BLOCKS - 1) / POOL_BLOCKS;  // 98
    int tid = threadIdx.x;
    int start = blockIdx.x * chunk;
    int end = start + chunk; if (end > N_NODES) end = N_NODES;
    if (start >= end) return;

    float acc = 0.f;
    int cur = batch[start];
    int cl = 0;
    for (int n = start; n < end; ++n) {
        int b = batch[n];
        if (b != cur) {
            atomicAdd(&pooled[cur * DIM + tid], acc);
            if (tid == 0) atomicAdd(&counts[cur], (float)cl);
            acc = 0.f; cl = 0; cur = b;
        }
        acc += b2f(hb[((size_t)n << 7) + tid]);
        ++cl;
    }
    atomicAdd(&pooled[cur * DIM + tid], acc);
    if (tid == 0) atomicAdd(&counts[cur], (float)cl);
}

// ---------------- head ----------------
__global__ void final_k(const float* __restrict__ pooled, const float* __restrict__ counts,
                        const float* __restrict__ Wf, const float* __restrict__ bf,
                        float* __restrict__ out) {
    __shared__ float sred[2];
    int gidx = blockIdx.x;
    int tid = threadIdx.x;   // 128
    float c = fmaxf(counts[gidx], 1.0f);
    float v = pooled[gidx * DIM + tid] / c * Wf[tid];
    for (int off = 32; off > 0; off >>= 1) v += __shfl_down(v, off, 64);
    if ((tid & 63) == 0) sred[tid >> 6] = v;
    __syncthreads();
    if (tid == 0) {
        float t = sred[0] + sred[1] + bf[0];
        out[gidx] = 1.0f / (1.0f + expf(-t));
    }
}

extern "C" void kernel_launch(void* const* d_in, const int* in_sizes, int n_in,
                              void* d_out, int out_size, void* d_ws, size_t ws_size,
                              hipStream_t stream) {
    const float* x     = (const float*)d_in[0];
    const int*   ei    = (const int*)d_in[1];
    const int*   batch = (const int*)d_in[2];
    const float* W1 = (const float*)d_in[3];  const float* b1 = (const float*)d_in[4];
    const float* W2 = (const float*)d_in[5];  const float* b2 = (const float*)d_in[6];
    const float* W3 = (const float*)d_in[7];  const float* b3 = (const float*)d_in[8];
    const float* Wf = (const float*)d_in[9];  const float* bf = (const float*)d_in[10];
    const int* rowp = ei;              // sources
    const int* colp = ei + N_EDGES;    // targets

    char* ws = (char*)d_ws;
    size_t o = 0;
    auto alloc = [&](size_t bytes) -> void* {
        void* p = ws + o;
        o += (bytes + 255) & ~(size_t)255;
        return p;
    };
    int*    cnt    = (int*)   alloc((size_t)N_NODES * 4);
    int*    offs   = (int*)   alloc((size_t)N_NODES * 4);
    int*    gfill  = (int*)   alloc(256 * 4);
    int*    part   = (int*)   alloc(1024 * 4);
    float*  dis    = (float*) alloc((size_t)N_NODES * 4);
    int*    csr    = (int*)   alloc((size_t)N_EDGES * 4);
    uint32* packed = (uint32*)alloc((size_t)N_EDGES * 4);
    float*  pooled = (float*) alloc((size_t)(N_GRAPHS * DIM + N_GRAPHS) * 4);
    ushort* wt     = (ushort*)alloc((size_t)DIM * DIM * 2);
    ushort* bufA   = (ushort*)alloc((size_t)N_NODES * DIM * 2);
    ushort* bufB   = (ushort*)alloc((size_t)N_NODES * DIM * 2);
    float*  counts = pooled + N_GRAPHS * DIM;

    hipMemsetAsync(cnt, 0, (size_t)N_NODES * 4, stream);
    hipMemsetAsync(pooled, 0, (size_t)(N_GRAPHS * DIM + N_GRAPHS) * 4, stream);

    int nb = (N_NODES + 511) / 512;
    count_k<<<512, 256, 0, stream>>>(colp, cnt);
    scan1_k<<<nb, 512, 0, stream>>>(cnt, offs, part);
    scan2_k<<<1, 64, 0, stream>>>(part, nb);
    scan3_k<<<(N_NODES + 255) / 256, 256, 0, stream>>>(offs, part, cnt, dis);
    initb_k<<<1, 256, 0, stream>>>(offs, gfill);
    bin_k<<<PB1, 256, 0, stream>>>(colp, rowp, gfill, packed);
    fill2_k<<<NBUK, 256, 0, stream>>>(packed, offs, csr);

    conv_k<<<(N_NODES * DIM / 4 + 255) / 256, 256, 0, stream>>>(x, bufB);

    const int GB = (N_NODES + 63) / 64;   // 782

    // layer 1
    wtr_k<<<64, 256, 0, stream>>>(W1, wt);
    gemm_mfma_k<<<GB, 256, 0, stream>>>(bufB, wt, dis, bufA);
    agg_k<<<(N_NODES + 3) / 4, 256, 0, stream>>>(bufA, dis, csr, offs, cnt, b1, bufB);
    // layer 2
    wtr_k<<<64, 256, 0, stream>>>(W2, wt);
    gemm_mfma_k<<<GB, 256, 0, stream>>>(bufB, wt, dis, bufA);
    agg_k<<<(N_NODES + 3) / 4, 256, 0, stream>>>(bufA, dis, csr, offs, cnt, b2, bufB);
    // layer 3
    wtr_k<<<64, 256, 0, stream>>>(W3, wt);
    gemm_mfma_k<<<GB, 256, 0, stream>>>(bufB, wt, dis, bufA);
    agg_k<<<(N_NODES + 3) / 4, 256, 0, stream>>>(bufA, dis, csr, offs, cnt, b3, bufB);

    pool_k<<<POOL_BLOCKS, 128, 0, stream>>>(bufB, batch, pooled, counts);
    final_k<<<N_GRAPHS, 128, 0, stream>>>(pooled, counts, Wf, bf, (float*)d_out);
}

// Round 6
// 322.487 us; speedup vs baseline: 3.3529x; 1.2404x over previous
//
#include <hip/hip_runtime.h>
#include <math.h>

#define N_NODES 50000
#define N_EDGES 1600000
#define DIM     128
#define N_GRAPHS 64

typedef unsigned int uint32;
typedef __attribute__((ext_vector_type(8))) short bf16x8;
typedef __attribute__((ext_vector_type(4))) float f32x4;

static __device__ __forceinline__ ushort f2b(float f) {
    uint32 u = __float_as_uint(f);
    uint32 r = (u + 0x7fffu + ((u >> 16) & 1u)) >> 16;   // RNE
    return (ushort)r;
}
static __device__ __forceinline__ float b2f(ushort h) {
    return __uint_as_float(((uint32)h) << 16);
}

// ---- bucketed CSR build (no node-level global atomics anywhere) ----
#define NBUK 196             // ceil(50000/256), bucket = node >> 8
#define CAP  16384           // slack per bucket (mean 8192, sd ~90)
#define PB1  400
#define CHUNK1 (N_EDGES / PB1)   // 4000 exact

__global__ void initg_k(int* __restrict__ gfill) {
    int t = threadIdx.x;
    if (t < NBUK) gfill[t] = t * CAP;
}

// pass 1: bin edges into per-bucket slack regions; runs are block-private.
__global__ __launch_bounds__(256) void bin_k(const int* __restrict__ col,
                                             const int* __restrict__ row,
                                             int* __restrict__ gfill,
                                             uint32* __restrict__ packed) {
    __shared__ int hist[NBUK];
    __shared__ int cur[NBUK];
    int tid = threadIdx.x;
    for (int t = tid; t < NBUK; t += 256) hist[t] = 0;
    __syncthreads();
    int start = blockIdx.x * CHUNK1, end = start + CHUNK1;
    for (int e = start + tid; e < end; e += 256)
        atomicAdd(&hist[col[e] >> 8], 1);
    __syncthreads();
    for (int t = tid; t < NBUK; t += 256) {
        int h = hist[t];
        cur[t] = h ? atomicAdd(&gfill[t], h) : 0;
    }
    __syncthreads();
    for (int e = start + tid; e < end; e += 256) {
        int c = col[e];
        int r = row[e];
        int pos = atomicAdd(&cur[c >> 8], 1);
        packed[pos] = ((uint32)(c & 255) << 16) | (uint32)r;
    }
}

// bucket sizes -> exclusive bases
__global__ void bscan_k(const int* __restrict__ gfill, int* __restrict__ bbase) {
    __shared__ int sm[256];
    int t = threadIdx.x;
    int v = (t < NBUK) ? (gfill[t] - t * CAP) : 0;
    sm[t] = v;
    __syncthreads();
    for (int off = 1; off < 256; off <<= 1) {
        int u = 0;
        if (t >= off) u = sm[t - off];
        __syncthreads();
        if (t >= off) sm[t] += u;
        __syncthreads();
    }
    if (t < NBUK) bbase[t] = sm[t] - v;
}

// pass 2: per bucket: histogram -> cnt/offs/dis, then rank-scatter csr.
__global__ __launch_bounds__(256) void bucket_k(const uint32* __restrict__ packed,
                                                const int* __restrict__ gfill,
                                                const int* __restrict__ bbase,
                                                int* __restrict__ cnt,
                                                int* __restrict__ offs,
                                                float* __restrict__ dis,
                                                int* __restrict__ csr) {
    __shared__ int hist[256];
    __shared__ int sm[256];
    __shared__ int lo[256];
    __shared__ int rank[256];
    int b = blockIdx.x, tid = threadIdx.x;
    int size = gfill[b] - b * CAP;
    const uint32* pk = packed + (size_t)b * CAP;
    hist[tid] = 0; rank[tid] = 0;
    __syncthreads();
    for (int e = tid; e < size; e += 256) atomicAdd(&hist[pk[e] >> 16], 1);
    __syncthreads();
    int h = hist[tid];
    sm[tid] = h;
    __syncthreads();
    for (int off = 1; off < 256; off <<= 1) {
        int u = 0;
        if (tid >= off) u = sm[tid - off];
        __syncthreads();
        if (tid >= off) sm[tid] += u;
        __syncthreads();
    }
    lo[tid] = sm[tid] - h;
    int gb = bbase[b];
    int node = (b << 8) + tid;
    if (node < N_NODES) {
        cnt[node]  = h;
        offs[node] = gb + lo[tid];
        dis[node]  = rsqrtf((float)h + 1.0f);
    }
    __syncthreads();
    for (int e = tid; e < size; e += 256) {
        uint32 p = pk[e];
        int cl = p >> 16;
        int r = atomicAdd(&rank[cl], 1);
        csr[gb + lo[cl] + r] = (int)(p & 0xffffu);
    }
}

// ---------------- fp32 -> bf16 convert ----------------
__global__ __launch_bounds__(256) void conv_k(const float* __restrict__ x, ushort* __restrict__ xb) {
    int i = blockIdx.x * blockDim.x + threadIdx.x;
    const int n4 = N_NODES * DIM / 4;
    if (i >= n4) return;
    float4 v = ((const float4*)x)[i];
    ushort4 o;
    o.x = f2b(v.x); o.y = f2b(v.y); o.z = f2b(v.z); o.w = f2b(v.w);
    ((ushort4*)xb)[i] = o;
}

// ---------------- W (fp32, row-major [k][n]) -> wt (bf16, [n][k]) ----------------
__global__ __launch_bounds__(256) void wtr_k(const float* __restrict__ W, ushort* __restrict__ wt) {
    int t = blockIdx.x * 256 + threadIdx.x;   // 0..16383
    int n = t >> 7, k = t & 127;
    wt[n * 128 + k] = f2b(W[k * 128 + n]);
}

// ---------------- g = bf16( (h_bf @ W) * dis )  via MFMA ----------------
__global__ __launch_bounds__(256) void gemm_mfma_k(const ushort* __restrict__ xb,
                                                   const ushort* __restrict__ wt,
                                                   const float* __restrict__ dis,
                                                   ushort* __restrict__ gb) {
    int wid  = threadIdx.x >> 6;
    int lane = threadIdx.x & 63;
    int r0 = blockIdx.x * 64 + wid * 16;
    int m  = lane & 15;
    int kg = lane >> 4;

    int arow = r0 + m;
    if (arow >= N_NODES) arow = N_NODES - 1;   // clamp; results discarded on store
    const ushort* abase = xb + (size_t)arow * DIM + kg * 8;
    const ushort* wbase = wt + (size_t)m * DIM + kg * 8;

    f32x4 acc[8];
    #pragma unroll
    for (int nt = 0; nt < 8; ++nt) acc[nt] = (f32x4){0.f, 0.f, 0.f, 0.f};

    #pragma unroll
    for (int kb = 0; kb < 4; ++kb) {
        bf16x8 a = *(const bf16x8*)(abase + kb * 32);
        #pragma unroll
        for (int nt = 0; nt < 8; ++nt) {
            bf16x8 b = *(const bf16x8*)(wbase + (size_t)nt * 16 * DIM + kb * 32);
            acc[nt] = __builtin_amdgcn_mfma_f32_16x16x32_bf16(a, b, acc[nt], 0, 0, 0);
        }
    }

    int orow0 = r0 + kg * 4;
    float dsc[4];
    #pragma unroll
    for (int i = 0; i < 4; ++i) {
        int rr = orow0 + i;
        dsc[i] = (rr < N_NODES) ? dis[rr] : 0.f;
    }
    #pragma unroll
    for (int i = 0; i < 4; ++i) {
        int rr = orow0 + i;
        if (rr >= N_NODES) continue;
        ushort* orow = gb + (size_t)rr * DIM + m;
        #pragma unroll
        for (int nt = 0; nt < 8; ++nt)
            orow[nt * 16] = f2b(acc[nt][i] * dsc[i]);
    }
}

// ---------------- out = bf16( relu(dis_i * (g_i + sum_j g_j) + b) ) ----------------
__global__ __launch_bounds__(256) void agg_k(const ushort* __restrict__ gb,
                                             const float* __restrict__ dis,
                                             const int* __restrict__ csr,
                                             const int* __restrict__ offs,
                                             const int* __restrict__ cnt,
                                             const float* __restrict__ bias,
                                             ushort* __restrict__ outb) {
    int lane = threadIdx.x & 63;
    int node = blockIdx.x * 4 + (threadIdx.x >> 6);
    if (node >= N_NODES) return;

    uint32 s = *(const uint32*)(gb + ((size_t)node << 7) + (lane << 1));
    float2 acc;
    acc.x = __uint_as_float(s << 16);
    acc.y = __uint_as_float(s & 0xffff0000u);

    int base = offs[node];
    int c = cnt[node];
    for (int s0 = 0; s0 < c; s0 += 64) {
        int rem = c - s0;
        int m = rem < 64 ? rem : 64;
        int idx = 0;
        if (lane < m) idx = csr[base + s0 + lane];
        int t = 0;
        for (; t + 8 <= m; t += 8) {
            int j0 = __shfl(idx, t, 64),     j1 = __shfl(idx, t + 1, 64);
            int j2 = __shfl(idx, t + 2, 64), j3 = __shfl(idx, t + 3, 64);
            int j4 = __shfl(idx, t + 4, 64), j5 = __shfl(idx, t + 5, 64);
            int j6 = __shfl(idx, t + 6, 64), j7 = __shfl(idx, t + 7, 64);
            uint32 v0 = *(const uint32*)(gb + ((size_t)j0 << 7) + (lane << 1));
            uint32 v1 = *(const uint32*)(gb + ((size_t)j1 << 7) + (lane << 1));
            uint32 v2 = *(const uint32*)(gb + ((size_t)j2 << 7) + (lane << 1));
            uint32 v3 = *(const uint32*)(gb + ((size_t)j3 << 7) + (lane << 1));
            uint32 v4 = *(const uint32*)(gb + ((size_t)j4 << 7) + (lane << 1));
            uint32 v5 = *(const uint32*)(gb + ((size_t)j5 << 7) + (lane << 1));
            uint32 v6 = *(const uint32*)(gb + ((size_t)j6 << 7) + (lane << 1));
            uint32 v7 = *(const uint32*)(gb + ((size_t)j7 << 7) + (lane << 1));
            acc.x += __uint_as_float(v0 << 16); acc.y += __uint_as_float(v0 & 0xffff0000u);
            acc.x += __uint_as_float(v1 << 16); acc.y += __uint_as_float(v1 & 0xffff0000u);
            acc.x += __uint_as_float(v2 << 16); acc.y += __uint_as_float(v2 & 0xffff0000u);
            acc.x += __uint_as_float(v3 << 16); acc.y += __uint_as_float(v3 & 0xffff0000u);
            acc.x += __uint_as_float(v4 << 16); acc.y += __uint_as_float(v4 & 0xffff0000u);
            acc.x += __uint_as_float(v5 << 16); acc.y += __uint_as_float(v5 & 0xffff0000u);
            acc.x += __uint_as_float(v6 << 16); acc.y += __uint_as_float(v6 & 0xffff0000u);
            acc.x += __uint_as_float(v7 << 16); acc.y += __uint_as_float(v7 & 0xffff0000u);
        }
        for (; t < m; ++t) {
            int j = __shfl(idx, t, 64);
            uint32 v = *(const uint32*)(gb + ((size_t)j << 7) + (lane << 1));
            acc.x += __uint_as_float(v << 16);
            acc.y += __uint_as_float(v & 0xffff0000u);
        }
    }
    float d = dis[node];
    float bx = bias[lane * 2], by = bias[lane * 2 + 1];
    float ox = fmaxf(fmaf(acc.x, d, bx), 0.f);
    float oy = fmaxf(fmaf(acc.y, d, by), 0.f);
    uint32 packed = (uint32)f2b(ox) | ((uint32)f2b(oy) << 16);
    *(uint32*)(outb + ((size_t)node << 7) + (lane << 1)) = packed;
}

// ---------------- mean-pool ----------------
#define POOL_BLOCKS 512
__global__ __launch_bounds__(128) void pool_k(const ushort* __restrict__ hb,
                                              const int* __restrict__ batch,
                                              float* __restrict__ pooled,
                                              float* __restrict__ counts) {
    const int chunk = (N_NODES + POOL_BLOCKS - 1) / POOL_BLOCKS;  // 98
    int tid = threadIdx.x;
    int start = blockIdx.x * chunk;
    int end = start + chunk; if (end > N_NODES) end = N_NODES;
    if (start >= end) return;

    float acc = 0.f;
    int cur = batch[start];
    int cl = 0;
    for (int n = start; n < end; ++n) {
        int b = batch[n];
        if (b != cur) {
            atomicAdd(&pooled[cur * DIM + tid], acc);
            if (tid == 0) atomicAdd(&counts[cur], (float)cl);
            acc = 0.f; cl = 0; cur = b;
        }
        acc += b2f(hb[((size_t)n << 7) + tid]);
        ++cl;
    }
    atomicAdd(&pooled[cur * DIM + tid], acc);
    if (tid == 0) atomicAdd(&counts[cur], (float)cl);
}

// ---------------- head ----------------
__global__ void final_k(const float* __restrict__ pooled, const float* __restrict__ counts,
                        const float* __restrict__ Wf, const float* __restrict__ bf,
                        float* __restrict__ out) {
    __shared__ float sred[2];
    int gidx = blockIdx.x;
    int tid = threadIdx.x;   // 128
    float c = fmaxf(counts[gidx], 1.0f);
    float v = pooled[gidx * DIM + tid] / c * Wf[tid];
    for (int off = 32; off > 0; off >>= 1) v += __shfl_down(v, off, 64);
    if ((tid & 63) == 0) sred[tid >> 6] = v;
    __syncthreads();
    if (tid == 0) {
        float t = sred[0] + sred[1] + bf[0];
        out[gidx] = 1.0f / (1.0f + expf(-t));
    }
}

extern "C" void kernel_launch(void* const* d_in, const int* in_sizes, int n_in,
                              void* d_out, int out_size, void* d_ws, size_t ws_size,
                              hipStream_t stream) {
    const float* x     = (const float*)d_in[0];
    const int*   ei    = (const int*)d_in[1];
    const int*   batch = (const int*)d_in[2];
    const float* W1 = (const float*)d_in[3];  const float* b1 = (const float*)d_in[4];
    const float* W2 = (const float*)d_in[5];  const float* b2 = (const float*)d_in[6];
    const float* W3 = (const float*)d_in[7];  const float* b3 = (const float*)d_in[8];
    const float* Wf = (const float*)d_in[9];  const float* bf = (const float*)d_in[10];
    const int* rowp = ei;              // sources
    const int* colp = ei + N_EDGES;    // targets

    char* ws = (char*)d_ws;
    size_t o = 0;
    auto alloc = [&](size_t bytes) -> void* {
        void* p = ws + o;
        o += (bytes + 255) & ~(size_t)255;
        return p;
    };
    int*    cnt    = (int*)   alloc((size_t)N_NODES * 4);
    int*    offs   = (int*)   alloc((size_t)N_NODES * 4);
    int*    gfill  = (int*)   alloc(256 * 4);
    int*    bbase  = (int*)   alloc(256 * 4);
    float*  dis    = (float*) alloc((size_t)N_NODES * 4);
    int*    csr    = (int*)   alloc((size_t)N_EDGES * 4);
    uint32* packed = (uint32*)alloc((size_t)NBUK * CAP * 4);
    float*  pooled = (float*) alloc((size_t)(N_GRAPHS * DIM + N_GRAPHS) * 4);
    ushort* wt     = (ushort*)alloc((size_t)DIM * DIM * 2);
    ushort* bufA   = (ushort*)alloc((size_t)N_NODES * DIM * 2);
    ushort* bufB   = (ushort*)alloc((size_t)N_NODES * DIM * 2);
    float*  counts = pooled + N_GRAPHS * DIM;

    hipMemsetAsync(pooled, 0, (size_t)(N_GRAPHS * DIM + N_GRAPHS) * 4, stream);

    initg_k<<<1, 256, 0, stream>>>(gfill);
    bin_k<<<PB1, 256, 0, stream>>>(colp, rowp, gfill, packed);
    bscan_k<<<1, 256, 0, stream>>>(gfill, bbase);
    bucket_k<<<NBUK, 256, 0, stream>>>(packed, gfill, bbase, cnt, offs, dis, csr);

    conv_k<<<(N_NODES * DIM / 4 + 255) / 256, 256, 0, stream>>>(x, bufB);

    const int GB = (N_NODES + 63) / 64;   // 782

    // layer 1
    wtr_k<<<64, 256, 0, stream>>>(W1, wt);
    gemm_mfma_k<<<GB, 256, 0, stream>>>(bufB, wt, dis, bufA);
    agg_k<<<(N_NODES + 3) / 4, 256, 0, stream>>>(bufA, dis, csr, offs, cnt, b1, bufB);
    // layer 2
    wtr_k<<<64, 256, 0, stream>>>(W2, wt);
    gemm_mfma_k<<<GB, 256, 0, stream>>>(bufB, wt, dis, bufA);
    agg_k<<<(N_NODES + 3) / 4, 256, 0, stream>>>(bufA, dis, csr, offs, cnt, b2, bufB);
    // layer 3
    wtr_k<<<64, 256, 0, stream>>>(W3, wt);
    gemm_mfma_k<<<GB, 256, 0, stream>>>(bufB, wt, dis, bufA);
    agg_k<<<(N_NODES + 3) / 4, 256, 0, stream>>>(bufA, dis, csr, offs, cnt, b3, bufB);

    pool_k<<<POOL_BLOCKS, 128, 0, stream>>>(bufB, batch, pooled, counts);
    final_k<<<N_GRAPHS, 128, 0, stream>>>(pooled, counts, Wf, bf, (float*)d_out);
}

// Round 7
// 291.015 us; speedup vs baseline: 3.7156x; 1.1081x over previous
//
#include <hip/hip_runtime.h>
#include <hip/hip_fp16.h>
#include <math.h>

#define N_NODES 50000
#define N_EDGES 1600000
#define DIM     128
#define N_GRAPHS 64

typedef unsigned int uint32;
typedef __attribute__((ext_vector_type(8))) short bf16x8;
typedef __attribute__((ext_vector_type(4))) float f32x4;

static __device__ __forceinline__ ushort f2b(float f) {
    uint32 u = __float_as_uint(f);
    uint32 r = (u + 0x7fffu + ((u >> 16) & 1u)) >> 16;   // RNE
    return (ushort)r;
}
static __device__ __forceinline__ float b2f(ushort h) {
    return __uint_as_float(((uint32)h) << 16);
}
// fp8 e5m2 = top byte of fp16. Encode f32 -> f16 (RNE) -> RNE to top byte.
static __device__ __forceinline__ unsigned char f2e5(float f) {
    ushort hb = __half_as_ushort(__float2half(f));
    return (unsigned char)(((uint32)hb + 0x7fu + ((hb >> 8) & 1u)) >> 8);
}
static __device__ __forceinline__ float e5lo(uint32 v) {   // low byte of ushort
    return __half2float(__ushort_as_half((ushort)((v << 8) & 0xff00u)));
}
static __device__ __forceinline__ float e5hi(uint32 v) {   // high byte
    return __half2float(__ushort_as_half((ushort)(v & 0xff00u)));
}

// ---- bucketed CSR build (no node-level global atomics anywhere) ----
#define NBUK 196             // ceil(50000/256), bucket = node >> 8
#define CAP  16384           // slack per bucket (mean 8192, sd ~90)
#define PB1  400
#define CHUNK1 (N_EDGES / PB1)   // 4000 exact

__global__ void initg_k(int* __restrict__ gfill) {
    int t = threadIdx.x;
    if (t < NBUK) gfill[t] = t * CAP;
}

__global__ __launch_bounds__(256) void bin_k(const int* __restrict__ col,
                                             const int* __restrict__ row,
                                             int* __restrict__ gfill,
                                             uint32* __restrict__ packed) {
    __shared__ int hist[NBUK];
    __shared__ int cur[NBUK];
    int tid = threadIdx.x;
    for (int t = tid; t < NBUK; t += 256) hist[t] = 0;
    __syncthreads();
    int start = blockIdx.x * CHUNK1, end = start + CHUNK1;
    for (int e = start + tid; e < end; e += 256)
        atomicAdd(&hist[col[e] >> 8], 1);
    __syncthreads();
    for (int t = tid; t < NBUK; t += 256) {
        int h = hist[t];
        cur[t] = h ? atomicAdd(&gfill[t], h) : 0;
    }
    __syncthreads();
    for (int e = start + tid; e < end; e += 256) {
        int c = col[e];
        int r = row[e];
        int pos = atomicAdd(&cur[c >> 8], 1);
        packed[pos] = ((uint32)(c & 255) << 16) | (uint32)r;
    }
}

__global__ void bscan_k(const int* __restrict__ gfill, int* __restrict__ bbase) {
    __shared__ int sm[256];
    int t = threadIdx.x;
    int v = (t < NBUK) ? (gfill[t] - t * CAP) : 0;
    sm[t] = v;
    __syncthreads();
    for (int off = 1; off < 256; off <<= 1) {
        int u = 0;
        if (t >= off) u = sm[t - off];
        __syncthreads();
        if (t >= off) sm[t] += u;
        __syncthreads();
    }
    if (t < NBUK) bbase[t] = sm[t] - v;
}

__global__ __launch_bounds__(256) void bucket_k(const uint32* __restrict__ packed,
                                                const int* __restrict__ gfill,
                                                const int* __restrict__ bbase,
                                                int* __restrict__ cnt,
                                                int* __restrict__ offs,
                                                float* __restrict__ dis,
                                                int* __restrict__ csr) {
    __shared__ int hist[256];
    __shared__ int sm[256];
    __shared__ int lo[256];
    __shared__ int rank[256];
    int b = blockIdx.x, tid = threadIdx.x;
    int size = gfill[b] - b * CAP;
    const uint32* pk = packed + (size_t)b * CAP;
    hist[tid] = 0; rank[tid] = 0;
    __syncthreads();
    for (int e = tid; e < size; e += 256) atomicAdd(&hist[pk[e] >> 16], 1);
    __syncthreads();
    int h = hist[tid];
    sm[tid] = h;
    __syncthreads();
    for (int off = 1; off < 256; off <<= 1) {
        int u = 0;
        if (tid >= off) u = sm[tid - off];
        __syncthreads();
        if (tid >= off) sm[tid] += u;
        __syncthreads();
    }
    lo[tid] = sm[tid] - h;
    int gb = bbase[b];
    int node = (b << 8) + tid;
    if (node < N_NODES) {
        cnt[node]  = h;
        offs[node] = gb + lo[tid];
        dis[node]  = rsqrtf((float)h + 1.0f);
    }
    __syncthreads();
    for (int e = tid; e < size; e += 256) {
        uint32 p = pk[e];
        int cl = p >> 16;
        int r = atomicAdd(&rank[cl], 1);
        csr[gb + lo[cl] + r] = (int)(p & 0xffffu);
    }
}

// ---------------- fp32 -> bf16 convert ----------------
__global__ __launch_bounds__(256) void conv_k(const float* __restrict__ x, ushort* __restrict__ xb) {
    int i = blockIdx.x * blockDim.x + threadIdx.x;
    const int n4 = N_NODES * DIM / 4;
    if (i >= n4) return;
    float4 v = ((const float4*)x)[i];
    ushort4 o;
    o.x = f2b(v.x); o.y = f2b(v.y); o.z = f2b(v.z); o.w = f2b(v.w);
    ((ushort4*)xb)[i] = o;
}

// ---------------- W (fp32, row-major [k][n]) -> wt (bf16, [n][k]) ----------------
__global__ __launch_bounds__(256) void wtr_k(const float* __restrict__ W, ushort* __restrict__ wt) {
    int t = blockIdx.x * 256 + threadIdx.x;   // 0..16383
    int n = t >> 7, k = t & 127;
    wt[n * 128 + k] = f2b(W[k * 128 + n]);
}

// ---------------- g = fp8e5m2( (h_bf @ W) * dis )  via MFMA ----------------
__global__ __launch_bounds__(256) void gemm_mfma_k(const ushort* __restrict__ xb,
                                                   const ushort* __restrict__ wt,
                                                   const float* __restrict__ dis,
                                                   unsigned char* __restrict__ gb) {
    int wid  = threadIdx.x >> 6;
    int lane = threadIdx.x & 63;
    int r0 = blockIdx.x * 64 + wid * 16;
    int m  = lane & 15;
    int kg = lane >> 4;

    int arow = r0 + m;
    if (arow >= N_NODES) arow = N_NODES - 1;   // clamp; results discarded on store
    const ushort* abase = xb + (size_t)arow * DIM + kg * 8;
    const ushort* wbase = wt + (size_t)m * DIM + kg * 8;

    f32x4 acc[8];
    #pragma unroll
    for (int nt = 0; nt < 8; ++nt) acc[nt] = (f32x4){0.f, 0.f, 0.f, 0.f};

    #pragma unroll
    for (int kb = 0; kb < 4; ++kb) {
        bf16x8 a = *(const bf16x8*)(abase + kb * 32);
        #pragma unroll
        for (int nt = 0; nt < 8; ++nt) {
            bf16x8 b = *(const bf16x8*)(wbase + (size_t)nt * 16 * DIM + kb * 32);
            acc[nt] = __builtin_amdgcn_mfma_f32_16x16x32_bf16(a, b, acc[nt], 0, 0, 0);
        }
    }

    int orow0 = r0 + kg * 4;
    float dsc[4];
    #pragma unroll
    for (int i = 0; i < 4; ++i) {
        int rr = orow0 + i;
        dsc[i] = (rr < N_NODES) ? dis[rr] : 0.f;
    }
    #pragma unroll
    for (int i = 0; i < 4; ++i) {
        int rr = orow0 + i;
        if (rr >= N_NODES) continue;
        unsigned char* orow = gb + (size_t)rr * DIM + m;
        #pragma unroll
        for (int nt = 0; nt < 8; ++nt)
            orow[nt * 16] = f2e5(acc[nt][i] * dsc[i]);
    }
}

// ---------------- out = bf16( relu(dis_i * (g_i + sum_j g_j) + b) ) ----------------
// g table is fp8 e5m2 (row = 128 B); lane holds 2 features.
__global__ __launch_bounds__(256) void agg_k(const unsigned char* __restrict__ gb,
                                             const float* __restrict__ dis,
                                             const int* __restrict__ csr,
                                             const int* __restrict__ offs,
                                             const int* __restrict__ cnt,
                                             const float* __restrict__ bias,
                                             ushort* __restrict__ outb) {
    int lane = threadIdx.x & 63;
    int node = blockIdx.x * 4 + (threadIdx.x >> 6);
    if (node >= N_NODES) return;

    uint32 s = *(const ushort*)(gb + ((size_t)node << 7) + (lane << 1));
    float2 acc;
    acc.x = e5lo(s);
    acc.y = e5hi(s);

    int base = offs[node];
    int c = cnt[node];
    for (int s0 = 0; s0 < c; s0 += 64) {
        int rem = c - s0;
        int m = rem < 64 ? rem : 64;
        int idx = 0;
        if (lane < m) idx = csr[base + s0 + lane];
        int t = 0;
        for (; t + 8 <= m; t += 8) {
            int j0 = __shfl(idx, t, 64),     j1 = __shfl(idx, t + 1, 64);
            int j2 = __shfl(idx, t + 2, 64), j3 = __shfl(idx, t + 3, 64);
            int j4 = __shfl(idx, t + 4, 64), j5 = __shfl(idx, t + 5, 64);
            int j6 = __shfl(idx, t + 6, 64), j7 = __shfl(idx, t + 7, 64);
            uint32 v0 = *(const ushort*)(gb + ((size_t)j0 << 7) + (lane << 1));
            uint32 v1 = *(const ushort*)(gb + ((size_t)j1 << 7) + (lane << 1));
            uint32 v2 = *(const ushort*)(gb + ((size_t)j2 << 7) + (lane << 1));
            uint32 v3 = *(const ushort*)(gb + ((size_t)j3 << 7) + (lane << 1));
            uint32 v4 = *(const ushort*)(gb + ((size_t)j4 << 7) + (lane << 1));
            uint32 v5 = *(const ushort*)(gb + ((size_t)j5 << 7) + (lane << 1));
            uint32 v6 = *(const ushort*)(gb + ((size_t)j6 << 7) + (lane << 1));
            uint32 v7 = *(const ushort*)(gb + ((size_t)j7 << 7) + (lane << 1));
            acc.x += e5lo(v0); acc.y += e5hi(v0);
            acc.x += e5lo(v1); acc.y += e5hi(v1);
            acc.x += e5lo(v2); acc.y += e5hi(v2);
            acc.x += e5lo(v3); acc.y += e5hi(v3);
            acc.x += e5lo(v4); acc.y += e5hi(v4);
            acc.x += e5lo(v5); acc.y += e5hi(v5);
            acc.x += e5lo(v6); acc.y += e5hi(v6);
            acc.x += e5lo(v7); acc.y += e5hi(v7);
        }
        for (; t < m; ++t) {
            int j = __shfl(idx, t, 64);
            uint32 v = *(const ushort*)(gb + ((size_t)j << 7) + (lane << 1));
            acc.x += e5lo(v);
            acc.y += e5hi(v);
        }
    }
    float d = dis[node];
    float bx = bias[lane * 2], by = bias[lane * 2 + 1];
    float ox = fmaxf(fmaf(acc.x, d, bx), 0.f);
    float oy = fmaxf(fmaf(acc.y, d, by), 0.f);
    uint32 packed = (uint32)f2b(ox) | ((uint32)f2b(oy) << 16);
    *(uint32*)(outb + ((size_t)node << 7) + (lane << 1)) = packed;
}

// ---------------- mean-pool ----------------
#define POOL_BLOCKS 512
__global__ __launch_bounds__(128) void pool_k(const ushort* __restrict__ hb,
                                              const int* __restrict__ batch,
                                              float* __restrict__ pooled,
                                              float* __restrict__ counts) {
    const int chunk = (N_NODES + POOL_BLOCKS - 1) / POOL_BLOCKS;  // 98
    int tid = threadIdx.x;
    int start = blockIdx.x * chunk;
    int end = start + chunk; if (end > N_NODES) end = N_NODES;
    if (start >= end) return;

    float acc = 0.f;
    int cur = batch[start];
    int cl = 0;
    for (int n = start; n < end; ++n) {
        int b = batch[n];
        if (b != cur) {
            atomicAdd(&pooled[cur * DIM + tid], acc);
            if (tid == 0) atomicAdd(&counts[cur], (float)cl);
            acc = 0.f; cl = 0; cur = b;
        }
        acc += b2f(hb[((size_t)n << 7) + tid]);
        ++cl;
    }
    atomicAdd(&pooled[cur * DIM + tid], acc);
    if (tid == 0) atomicAdd(&counts[cur], (float)cl);
}

// ---------------- head ----------------
__global__ void final_k(const float* __restrict__ pooled, const float* __restrict__ counts,
                        const float* __restrict__ Wf, const float* __restrict__ bf,
                        float* __restrict__ out) {
    __shared__ float sred[2];
    int gidx = blockIdx.x;
    int tid = threadIdx.x;   // 128
    float c = fmaxf(counts[gidx], 1.0f);
    float v = pooled[gidx * DIM + tid] / c * Wf[tid];
    for (int off = 32; off > 0; off >>= 1) v += __shfl_down(v, off, 64);
    if ((tid & 63) == 0) sred[tid >> 6] = v;
    __syncthreads();
    if (tid == 0) {
        float t = sred[0] + sred[1] + bf[0];
        out[gidx] = 1.0f / (1.0f + expf(-t));
    }
}

extern "C" void kernel_launch(void* const* d_in, const int* in_sizes, int n_in,
                              void* d_out, int out_size, void* d_ws, size_t ws_size,
                              hipStream_t stream) {
    const float* x     = (const float*)d_in[0];
    const int*   ei    = (const int*)d_in[1];
    const int*   batch = (const int*)d_in[2];
    const float* W1 = (const float*)d_in[3];  const float* b1 = (const float*)d_in[4];
    const float* W2 = (const float*)d_in[5];  const float* b2 = (const float*)d_in[6];
    const float* W3 = (const float*)d_in[7];  const float* b3 = (const float*)d_in[8];
    const float* Wf = (const float*)d_in[9];  const float* bf = (const float*)d_in[10];
    const int* rowp = ei;              // sources
    const int* colp = ei + N_EDGES;    // targets

    char* ws = (char*)d_ws;
    size_t o = 0;
    auto alloc = [&](size_t bytes) -> void* {
        void* p = ws + o;
        o += (bytes + 255) & ~(size_t)255;
        return p;
    };
    int*    cnt    = (int*)   alloc((size_t)N_NODES * 4);
    int*    offs   = (int*)   alloc((size_t)N_NODES * 4);
    int*    gfill  = (int*)   alloc(256 * 4);
    int*    bbase  = (int*)   alloc(256 * 4);
    float*  dis    = (float*) alloc((size_t)N_NODES * 4);
    int*    csr    = (int*)   alloc((size_t)N_EDGES * 4);
    uint32* packed = (uint32*)alloc((size_t)NBUK * CAP * 4);
    float*  pooled = (float*) alloc((size_t)(N_GRAPHS * DIM + N_GRAPHS) * 4);
    ushort* wt     = (ushort*)alloc((size_t)DIM * DIM * 2);
    unsigned char* bufA = (unsigned char*)alloc((size_t)N_NODES * DIM);  // g (fp8)
    ushort* bufB   = (ushort*)alloc((size_t)N_NODES * DIM * 2);          // h (bf16)
    float*  counts = pooled + N_GRAPHS * DIM;

    hipMemsetAsync(pooled, 0, (size_t)(N_GRAPHS * DIM + N_GRAPHS) * 4, stream);

    initg_k<<<1, 256, 0, stream>>>(gfill);
    bin_k<<<PB1, 256, 0, stream>>>(colp, rowp, gfill, packed);
    bscan_k<<<1, 256, 0, stream>>>(gfill, bbase);
    bucket_k<<<NBUK, 256, 0, stream>>>(packed, gfill, bbase, cnt, offs, dis, csr);

    conv_k<<<(N_NODES * DIM / 4 + 255) / 256, 256, 0, stream>>>(x, bufB);

    const int GB = (N_NODES + 63) / 64;   // 782

    // layer 1
    wtr_k<<<64, 256, 0, stream>>>(W1, wt);
    gemm_mfma_k<<<GB, 256, 0, stream>>>(bufB, wt, dis, bufA);
    agg_k<<<(N_NODES + 3) / 4, 256, 0, stream>>>(bufA, dis, csr, offs, cnt, b1, bufB);
    // layer 2
    wtr_k<<<64, 256, 0, stream>>>(W2, wt);
    gemm_mfma_k<<<GB, 256, 0, stream>>>(bufB, wt, dis, bufA);
    agg_k<<<(N_NODES + 3) / 4, 256, 0, stream>>>(bufA, dis, csr, offs, cnt, b2, bufB);
    // layer 3
    wtr_k<<<64, 256, 0, stream>>>(W3, wt);
    gemm_mfma_k<<<GB, 256, 0, stream>>>(bufB, wt, dis, bufA);
    agg_k<<<(N_NODES + 3) / 4, 256, 0, stream>>>(bufA, dis, csr, offs, cnt, b3, bufB);

    pool_k<<<POOL_BLOCKS, 128, 0, stream>>>(bufB, batch, pooled, counts);
    final_k<<<N_GRAPHS, 128, 0, stream>>>(pooled, counts, Wf, bf, (float*)d_out);
}